// Round 1
// baseline (543.900 us; speedup 1.0000x reference)
//
#include <hip/hip_runtime.h>
#include <cstdint>
#include <cstddef>

#define NN 50000
#define IN_CH 128
#define C1 256        // HEADS*HID
#define HID 64
#define HEADS 4
#define OUT_CH 16
#define NEG_SLOPE 0.2f
#define EPS_SM 1e-16f

// ---------------- GEMM1: h1[N,256] = x[N,128] @ W1[128,256] ----------------
#define BM 64
#define BN 64
#define BK 16
__global__ __launch_bounds__(256) void gemm1_kernel(const float* __restrict__ A,
                                                    const float* __restrict__ B,
                                                    float* __restrict__ C,
                                                    int M, int K, int Ncol) {
    __shared__ float sA[BK][BM];
    __shared__ float sB[BK][BN];
    int tid = threadIdx.x;
    int m0 = blockIdx.y * BM, n0 = blockIdx.x * BN;
    float acc[4][4] = {};
    int tm = (tid & 15) * 4;
    int tn = (tid >> 4) * 4;
    for (int k0 = 0; k0 < K; k0 += BK) {
        // A tile: 64 rows x 16 k; each thread one float4 along k
        int lr = tid >> 2;
        int lc = (tid & 3) * 4;
        float4 av = make_float4(0.f, 0.f, 0.f, 0.f);
        if (m0 + lr < M) av = *(const float4*)&A[(size_t)(m0 + lr) * K + k0 + lc];
        sA[lc + 0][lr] = av.x; sA[lc + 1][lr] = av.y;
        sA[lc + 2][lr] = av.z; sA[lc + 3][lr] = av.w;
        // B tile: 16 k x 64 n
        int br = tid >> 4;
        int bc = (tid & 15) * 4;
        float4 bv = *(const float4*)&B[(size_t)(k0 + br) * Ncol + n0 + bc];
        *(float4*)&sB[br][bc] = bv;
        __syncthreads();
#pragma unroll
        for (int kk = 0; kk < BK; ++kk) {
            float4 a = *(const float4*)&sA[kk][tm];
            float4 b = *(const float4*)&sB[kk][tn];
            acc[0][0] += a.x * b.x; acc[0][1] += a.x * b.y; acc[0][2] += a.x * b.z; acc[0][3] += a.x * b.w;
            acc[1][0] += a.y * b.x; acc[1][1] += a.y * b.y; acc[1][2] += a.y * b.z; acc[1][3] += a.y * b.w;
            acc[2][0] += a.z * b.x; acc[2][1] += a.z * b.y; acc[2][2] += a.z * b.z; acc[2][3] += a.z * b.w;
            acc[3][0] += a.w * b.x; acc[3][1] += a.w * b.y; acc[3][2] += a.w * b.z; acc[3][3] += a.w * b.w;
        }
        __syncthreads();
    }
#pragma unroll
    for (int i = 0; i < 4; ++i) {
        if (m0 + tm + i < M) {
            float4 v = make_float4(acc[i][0], acc[i][1], acc[i][2], acc[i][3]);
            *(float4*)&C[(size_t)(m0 + tm + i) * Ncol + n0 + tn] = v;
        }
    }
}

// ---------------- scores1: s_src1[n,h] = dot(h1[n,h,:], a_src1[h,:]) -------
__global__ __launch_bounds__(256) void scores1_kernel(const float* __restrict__ h1,
                                                      const float* __restrict__ a_src,
                                                      const float* __restrict__ a_dst,
                                                      float* __restrict__ s_src,
                                                      float* __restrict__ s_dst) {
    int n = blockIdx.x;
    int w = threadIdx.x >> 6;   // head
    int lane = threadIdx.x & 63;
    float hv = h1[(size_t)n * C1 + w * HID + lane];
    float ps = hv * a_src[w * HID + lane];
    float pd = hv * a_dst[w * HID + lane];
#pragma unroll
    for (int o = 1; o < 64; o <<= 1) {
        ps += __shfl_xor(ps, o);
        pd += __shfl_xor(pd, o);
    }
    if (lane == 0) {
        s_src[n * HEADS + w] = ps;
        s_dst[n * HEADS + w] = pd;
    }
}

// ---------------- CSR build ----------------
__global__ void hist_kernel(const int* __restrict__ dst_arr, int* __restrict__ deg,
                            int Etot, int E) {
    for (int i = blockIdx.x * blockDim.x + threadIdx.x; i < Etot; i += gridDim.x * blockDim.x) {
        int dst = (i < E) ? dst_arr[i] : (i - E);
        atomicAdd(&deg[dst], 1);
    }
}

__global__ __launch_bounds__(1024) void scan_kernel(const int* __restrict__ deg,
                                                    int* __restrict__ row_start,
                                                    int* __restrict__ cursor, int n) {
    __shared__ int buf[1024];
    __shared__ int carry_s;
    int t = threadIdx.x;
    if (t == 0) carry_s = 0;
    __syncthreads();
    for (int base = 0; base < n; base += 1024) {
        int x = (base + t < n) ? deg[base + t] : 0;
        buf[t] = x;
        __syncthreads();
        for (int off = 1; off < 1024; off <<= 1) {
            int v = (t >= off) ? buf[t - off] : 0;
            __syncthreads();
            buf[t] += v;
            __syncthreads();
        }
        int carry = carry_s;
        if (base + t < n) {
            int excl = carry + buf[t] - x;
            row_start[base + t] = excl;
            cursor[base + t] = excl;
        }
        __syncthreads();
        if (t == 1023) carry_s = carry + buf[1023];
        __syncthreads();
    }
    if (t == 0) row_start[n] = carry_s;
}

__global__ void scatter_kernel(const int* __restrict__ dst_arr, int* __restrict__ cursor,
                               int* __restrict__ eids, int Etot, int E) {
    for (int i = blockIdx.x * blockDim.x + threadIdx.x; i < Etot; i += gridDim.x * blockDim.x) {
        int dst = (i < E) ? dst_arr[i] : (i - E);
        int pos = atomicAdd(&cursor[dst], 1);
        eids[pos] = i;
    }
}

// ---------------- layer-1 softmax + aggregate + bias + ELU -----------------
__global__ __launch_bounds__(256) void agg1_kernel(const float* __restrict__ h1,
                                                   const float* __restrict__ s_src1,
                                                   const float* __restrict__ s_dst1,
                                                   const int* __restrict__ row_start,
                                                   const int* __restrict__ eids,
                                                   const int* __restrict__ src_arr,
                                                   const float* __restrict__ b1,
                                                   float* __restrict__ out1, int E) {
    int d = blockIdx.x * 4 + (threadIdx.x >> 6);
    if (d >= NN) return;
    int lane = threadIdx.x & 63;
    int h = lane >> 4;
    int sub = lane & 15;
    int start = row_start[d], end = row_start[d + 1];
    float sdst = s_dst1[d * HEADS + h];

    float mx = -3.4e38f;
    for (int i = start + sub; i < end; i += 16) {
        int eid = eids[i];
        int src = (eid < E) ? src_arr[eid] : (eid - E);
        float e = s_src1[src * HEADS + h] + sdst;
        e = e > 0.f ? e : NEG_SLOPE * e;
        mx = fmaxf(mx, e);
    }
#pragma unroll
    for (int o = 1; o < 16; o <<= 1) mx = fmaxf(mx, __shfl_xor(mx, o));

    float ssum = 0.f;
    for (int i = start + sub; i < end; i += 16) {
        int eid = eids[i];
        int src = (eid < E) ? src_arr[eid] : (eid - E);
        float e = s_src1[src * HEADS + h] + sdst;
        e = e > 0.f ? e : NEG_SLOPE * e;
        ssum += __expf(e - mx);
    }
#pragma unroll
    for (int o = 1; o < 16; o <<= 1) ssum += __shfl_xor(ssum, o);
    float inv = 1.f / (ssum + EPS_SM);

    float4 acc = make_float4(0.f, 0.f, 0.f, 0.f);
    for (int i = start; i < end; ++i) {
        int eid = eids[i];
        int src = (eid < E) ? src_arr[eid] : (eid - E);
        float e = s_src1[src * HEADS + h] + sdst;
        e = e > 0.f ? e : NEG_SLOPE * e;
        float a = __expf(e - mx) * inv;
        float4 hv = *(const float4*)&h1[(size_t)src * C1 + lane * 4];
        acc.x += a * hv.x; acc.y += a * hv.y; acc.z += a * hv.z; acc.w += a * hv.w;
    }
    int cb = lane * 4;
    float v0 = acc.x + b1[cb + 0];
    float v1 = acc.y + b1[cb + 1];
    float v2 = acc.z + b1[cb + 2];
    float v3 = acc.w + b1[cb + 3];
    // ELU
    v0 = v0 > 0.f ? v0 : (__expf(v0) - 1.f);
    v1 = v1 > 0.f ? v1 : (__expf(v1) - 1.f);
    v2 = v2 > 0.f ? v2 : (__expf(v2) - 1.f);
    v3 = v3 > 0.f ? v3 : (__expf(v3) - 1.f);
    *(float4*)&out1[(size_t)d * C1 + cb] = make_float4(v0, v1, v2, v3);
}

// ---------------- layer-2 GEMM (K=256 -> 16) fused with scores -------------
__global__ __launch_bounds__(256) void gemm2_scores_kernel(const float* __restrict__ out1,
                                                           const float* __restrict__ W2,
                                                           const float* __restrict__ a_src2,
                                                           const float* __restrict__ a_dst2,
                                                           float* __restrict__ h2,
                                                           float* __restrict__ s_src2,
                                                           float* __restrict__ s_dst2) {
    int tid = threadIdx.x;
    int n = blockIdx.x * 16 + (tid >> 4);
    int c = tid & 15;
    if (n >= NN) return;
    const float* row = out1 + (size_t)n * C1;
    float acc = 0.f;
#pragma unroll 8
    for (int k = 0; k < C1; ++k) acc += row[k] * W2[k * OUT_CH + c];
    h2[(size_t)n * OUT_CH + c] = acc;
    float ps = acc * a_src2[c];
    float pd = acc * a_dst2[c];
#pragma unroll
    for (int o = 1; o < 16; o <<= 1) {
        ps += __shfl_xor(ps, o);
        pd += __shfl_xor(pd, o);
    }
    if (c == 0) {
        s_src2[n] = ps;
        s_dst2[n] = pd;
    }
}

// ---------------- layer-2 softmax + aggregate + bias -----------------------
__global__ __launch_bounds__(256) void agg2_kernel(const float* __restrict__ h2,
                                                   const float* __restrict__ s_src2,
                                                   const float* __restrict__ s_dst2,
                                                   const int* __restrict__ row_start,
                                                   const int* __restrict__ eids,
                                                   const int* __restrict__ src_arr,
                                                   const float* __restrict__ b2,
                                                   float* __restrict__ out, int E) {
    int d = blockIdx.x * 4 + (threadIdx.x >> 6);
    if (d >= NN) return;
    int lane = threadIdx.x & 63;
    int start = row_start[d], end = row_start[d + 1];
    float sdst = s_dst2[d];

    float mx = -3.4e38f;
    for (int i = start + lane; i < end; i += 64) {
        int eid = eids[i];
        int src = (eid < E) ? src_arr[eid] : (eid - E);
        float e = s_src2[src] + sdst;
        e = e > 0.f ? e : NEG_SLOPE * e;
        mx = fmaxf(mx, e);
    }
#pragma unroll
    for (int o = 1; o < 64; o <<= 1) mx = fmaxf(mx, __shfl_xor(mx, o));

    float ssum = 0.f;
    for (int i = start + lane; i < end; i += 64) {
        int eid = eids[i];
        int src = (eid < E) ? src_arr[eid] : (eid - E);
        float e = s_src2[src] + sdst;
        e = e > 0.f ? e : NEG_SLOPE * e;
        ssum += __expf(e - mx);
    }
#pragma unroll
    for (int o = 1; o < 64; o <<= 1) ssum += __shfl_xor(ssum, o);
    float inv = 1.f / (ssum + EPS_SM);

    int j = lane >> 4;   // edge slot 0..3
    int c = lane & 15;   // channel
    float acc = 0.f;
    for (int i = start + j; i < end; i += 4) {
        int eid = eids[i];
        int src = (eid < E) ? src_arr[eid] : (eid - E);
        float e = s_src2[src] + sdst;
        e = e > 0.f ? e : NEG_SLOPE * e;
        float a = __expf(e - mx) * inv;
        acc += a * h2[(size_t)src * OUT_CH + c];
    }
    acc += __shfl_xor(acc, 16);
    acc += __shfl_xor(acc, 32);
    if (lane < 16) out[(size_t)d * OUT_CH + c] = acc + b2[c];
}

extern "C" void kernel_launch(void* const* d_in, const int* in_sizes, int n_in,
                              void* d_out, int out_size, void* d_ws, size_t ws_size,
                              hipStream_t stream) {
    const float* x      = (const float*)d_in[0];
    const int*   ei     = (const int*)d_in[1];
    const float* W1     = (const float*)d_in[2];
    const float* a_src1 = (const float*)d_in[3];
    const float* a_dst1 = (const float*)d_in[4];
    const float* b1     = (const float*)d_in[5];
    const float* W2     = (const float*)d_in[6];
    const float* a_src2 = (const float*)d_in[7];
    const float* a_dst2 = (const float*)d_in[8];
    const float* b2     = (const float*)d_in[9];
    float* out = (float*)d_out;

    const int E = in_sizes[1] / 2;
    const int Etot = E + NN;
    const int* src_arr = ei;
    const int* dst_arr = ei + E;

    // ---- carve workspace ----
    size_t off = 0;
    auto carve = [&](size_t bytes) -> void* {
        void* r = (char*)d_ws + off;
        off += (bytes + 255) & ~(size_t)255;
        return r;
    };
    float* h1    = (float*)carve((size_t)NN * C1 * 4);
    float* out1  = (float*)carve((size_t)NN * C1 * 4);
    float* ssrc1 = (float*)carve((size_t)NN * HEADS * 4);
    float* sdst1 = (float*)carve((size_t)NN * HEADS * 4);
    float* h2    = (float*)carve((size_t)NN * OUT_CH * 4);
    float* ssrc2 = (float*)carve((size_t)NN * 4);
    float* sdst2 = (float*)carve((size_t)NN * 4);
    int* deg     = (int*)carve((size_t)NN * 4);
    int* rowst   = (int*)carve((size_t)(NN + 1) * 4);
    int* cursor  = (int*)carve((size_t)NN * 4);
    int* eids    = (int*)carve((size_t)Etot * 4);

    // ---- CSR build (independent of GEMM; launch first) ----
    hipMemsetAsync(deg, 0, (size_t)NN * 4, stream);
    hist_kernel<<<1024, 256, 0, stream>>>(dst_arr, deg, Etot, E);
    scan_kernel<<<1, 1024, 0, stream>>>(deg, rowst, cursor, NN);
    scatter_kernel<<<1024, 256, 0, stream>>>(dst_arr, cursor, eids, Etot, E);

    // ---- layer 1 ----
    dim3 g1(C1 / BN, (NN + BM - 1) / BM);
    gemm1_kernel<<<g1, 256, 0, stream>>>(x, W1, h1, NN, IN_CH, C1);
    scores1_kernel<<<NN, 256, 0, stream>>>(h1, a_src1, a_dst1, ssrc1, sdst1);
    agg1_kernel<<<(NN + 3) / 4, 256, 0, stream>>>(h1, ssrc1, sdst1, rowst, eids, src_arr,
                                                  b1, out1, E);

    // ---- layer 2 ----
    gemm2_scores_kernel<<<(NN + 15) / 16, 256, 0, stream>>>(out1, W2, a_src2, a_dst2,
                                                            h2, ssrc2, sdst2);
    agg2_kernel<<<(NN + 3) / 4, 256, 0, stream>>>(h2, ssrc2, sdst2, rowst, eids, src_arr,
                                                  b2, out, E);
}

// Round 2
// 380.552 us; speedup vs baseline: 1.4292x; 1.4292x over previous
//
#include <hip/hip_runtime.h>
#include <cstdint>
#include <cstddef>

#define NN 50000
#define IN_CH 128
#define C1 256        // HEADS*HID
#define HID 64
#define HEADS 4
#define OUT_CH 16
#define NEG_SLOPE 0.2f
#define EPS_SM 1e-16f

__device__ __forceinline__ unsigned short f2b(float f) {
    unsigned int u = __float_as_uint(f);
    u += 0x7fffu + ((u >> 16) & 1u);   // round-to-nearest-even
    return (unsigned short)(u >> 16);
}
__device__ __forceinline__ float b2f_lo(unsigned int packed) {
    return __uint_as_float(packed << 16);
}
__device__ __forceinline__ float b2f_hi(unsigned int packed) {
    return __uint_as_float(packed & 0xffff0000u);
}

// ---------------- GEMM1: h1b[N,256] = bf16( x[N,128] @ W1[128,256] ) -------
#define BM 64
#define BN 64
#define BK 16
__global__ __launch_bounds__(256) void gemm1_kernel(const float* __restrict__ A,
                                                    const float* __restrict__ B,
                                                    unsigned short* __restrict__ Cb,
                                                    int M, int K, int Ncol) {
    __shared__ float sA[BK][BM];
    __shared__ float sB[BK][BN];
    int tid = threadIdx.x;
    int m0 = blockIdx.y * BM, n0 = blockIdx.x * BN;
    float acc[4][4] = {};
    int tm = (tid & 15) * 4;
    int tn = (tid >> 4) * 4;
    for (int k0 = 0; k0 < K; k0 += BK) {
        int lr = tid >> 2;
        int lc = (tid & 3) * 4;
        float4 av = make_float4(0.f, 0.f, 0.f, 0.f);
        if (m0 + lr < M) av = *(const float4*)&A[(size_t)(m0 + lr) * K + k0 + lc];
        sA[lc + 0][lr] = av.x; sA[lc + 1][lr] = av.y;
        sA[lc + 2][lr] = av.z; sA[lc + 3][lr] = av.w;
        int br = tid >> 4;
        int bc = (tid & 15) * 4;
        float4 bv = *(const float4*)&B[(size_t)(k0 + br) * Ncol + n0 + bc];
        *(float4*)&sB[br][bc] = bv;
        __syncthreads();
#pragma unroll
        for (int kk = 0; kk < BK; ++kk) {
            float4 a = *(const float4*)&sA[kk][tm];
            float4 b = *(const float4*)&sB[kk][tn];
            acc[0][0] += a.x * b.x; acc[0][1] += a.x * b.y; acc[0][2] += a.x * b.z; acc[0][3] += a.x * b.w;
            acc[1][0] += a.y * b.x; acc[1][1] += a.y * b.y; acc[1][2] += a.y * b.z; acc[1][3] += a.y * b.w;
            acc[2][0] += a.z * b.x; acc[2][1] += a.z * b.y; acc[2][2] += a.z * b.z; acc[2][3] += a.z * b.w;
            acc[3][0] += a.w * b.x; acc[3][1] += a.w * b.y; acc[3][2] += a.w * b.z; acc[3][3] += a.w * b.w;
        }
        __syncthreads();
    }
#pragma unroll
    for (int i = 0; i < 4; ++i) {
        if (m0 + tm + i < M) {
            ushort4 v;
            v.x = f2b(acc[i][0]); v.y = f2b(acc[i][1]);
            v.z = f2b(acc[i][2]); v.w = f2b(acc[i][3]);
            *(ushort4*)&Cb[(size_t)(m0 + tm + i) * Ncol + n0 + tn] = v;
        }
    }
}

// ---------------- scores1 from bf16 h1 -------------------------------------
__global__ __launch_bounds__(256) void scores1_kernel(const unsigned short* __restrict__ h1b,
                                                      const float* __restrict__ a_src,
                                                      const float* __restrict__ a_dst,
                                                      float* __restrict__ s_src,
                                                      float* __restrict__ s_dst) {
    int n = blockIdx.x;
    int w = threadIdx.x >> 6;   // head
    int lane = threadIdx.x & 63;
    float hv = __uint_as_float((unsigned int)h1b[(size_t)n * C1 + w * HID + lane] << 16);
    float ps = hv * a_src[w * HID + lane];
    float pd = hv * a_dst[w * HID + lane];
#pragma unroll
    for (int o = 1; o < 64; o <<= 1) {
        ps += __shfl_xor(ps, o);
        pd += __shfl_xor(pd, o);
    }
    if (lane == 0) {
        s_src[n * HEADS + w] = ps;
        s_dst[n * HEADS + w] = pd;
    }
}

// ---------------- CSR build ----------------
__global__ void hist_kernel(const int* __restrict__ dst_arr, int* __restrict__ deg,
                            int Etot, int E) {
    for (int i = blockIdx.x * blockDim.x + threadIdx.x; i < Etot; i += gridDim.x * blockDim.x) {
        int dst = (i < E) ? dst_arr[i] : (i - E);
        atomicAdd(&deg[dst], 1);
    }
}

#define SCAN_CHUNK 1024
// per-block scan: 256 threads x 4 elements
__global__ __launch_bounds__(256) void scan_blk_kernel(const int* __restrict__ deg,
                                                       int* __restrict__ partial,
                                                       int* __restrict__ bsum, int n) {
    __shared__ int s[256];
    int t = threadIdx.x;
    int idx = blockIdx.x * SCAN_CHUNK + t * 4;
    int4 v = make_int4(0, 0, 0, 0);
    if (idx + 3 < n) v = *(const int4*)&deg[idx];
    else {
        if (idx < n) v.x = deg[idx];
        if (idx + 1 < n) v.y = deg[idx + 1];
        if (idx + 2 < n) v.z = deg[idx + 2];
    }
    int t1 = v.x, t2 = t1 + v.y, t3 = t2 + v.z, t4 = t3 + v.w;
    s[t] = t4;
    __syncthreads();
    for (int off = 1; off < 256; off <<= 1) {
        int x = (t >= off) ? s[t - off] : 0;
        __syncthreads();
        s[t] += x;
        __syncthreads();
    }
    int excl = s[t] - t4;
    if (t == 255) bsum[blockIdx.x] = s[255];
    if (idx < n) partial[idx] = excl;
    if (idx + 1 < n) partial[idx + 1] = excl + t1;
    if (idx + 2 < n) partial[idx + 2] = excl + t2;
    if (idx + 3 < n) partial[idx + 3] = excl + t3;
}

// scan of block sums (nb <= 64), one wave
__global__ void scan_bsum_kernel(int* __restrict__ bsum, int nb,
                                 int* __restrict__ row_start, int n, int total) {
    int t = threadIdx.x;   // 64 threads
    int v = (t < nb) ? bsum[t] : 0;
    int own = v;
#pragma unroll
    for (int off = 1; off < 64; off <<= 1) {
        int x = __shfl_up(v, off);
        if (t >= off) v += x;
    }
    if (t < nb) bsum[t] = v - own;   // exclusive
    if (t == 0) row_start[n] = total;
}

__global__ __launch_bounds__(256) void scan_add_kernel(const int* __restrict__ bsum,
                                                       int* __restrict__ row_start,
                                                       int* __restrict__ cursor, int n) {
    int base = blockIdx.x * SCAN_CHUNK;
    int off = bsum[blockIdx.x];
    for (int j = threadIdx.x; j < SCAN_CHUNK; j += 256) {
        int i = base + j;
        if (i < n) {
            int r = row_start[i] + off;
            row_start[i] = r;
            cursor[i] = r;
        }
    }
}

// scatter stores SRC node id directly (no eid indirection later)
__global__ void scatter_kernel(const int* __restrict__ src_arr, const int* __restrict__ dst_arr,
                               int* __restrict__ cursor, int* __restrict__ srcs,
                               int Etot, int E) {
    for (int i = blockIdx.x * blockDim.x + threadIdx.x; i < Etot; i += gridDim.x * blockDim.x) {
        int dst, src;
        if (i < E) { dst = dst_arr[i]; src = src_arr[i]; }
        else { dst = i - E; src = i - E; }
        int pos = atomicAdd(&cursor[dst], 1);
        srcs[pos] = src;
    }
}

// ---------------- layer-1 softmax (online) + aggregate + bias + ELU --------
__global__ __launch_bounds__(256) void agg1_kernel(const unsigned short* __restrict__ h1b,
                                                   const float* __restrict__ s_src1,
                                                   const float* __restrict__ s_dst1,
                                                   const int* __restrict__ row_start,
                                                   const int* __restrict__ srcs,
                                                   const float* __restrict__ b1,
                                                   float* __restrict__ out1) {
    int d = blockIdx.x * 4 + (threadIdx.x >> 6);
    if (d >= NN) return;
    int lane = threadIdx.x & 63;
    int h = lane >> 4;
    int sub = lane & 15;
    int start = row_start[d], end = row_start[d + 1];
    float sdst = s_dst1[d * HEADS + h];

    // online max+sum in one pass, 16 lanes per head stride the edge list
    float mx = -3.4e38f, ssum = 0.f;
    for (int i = start + sub; i < end; i += 16) {
        int src = srcs[i];
        float e = s_src1[src * HEADS + h] + sdst;
        e = e > 0.f ? e : NEG_SLOPE * e;
        float m2 = fmaxf(mx, e);
        ssum = ssum * __expf(mx - m2) + __expf(e - m2);
        mx = m2;
    }
#pragma unroll
    for (int o = 1; o < 16; o <<= 1) {
        float mo = __shfl_xor(mx, o);
        float so = __shfl_xor(ssum, o);
        float m2 = fmaxf(mx, mo);
        ssum = ssum * __expf(mx - m2) + so * __expf(mo - m2);
        mx = m2;
    }
    float inv = 1.f / (ssum + EPS_SM);

    float4 acc = make_float4(0.f, 0.f, 0.f, 0.f);
    for (int i = start; i < end; ++i) {
        int src = srcs[i];
        float e = s_src1[src * HEADS + h] + sdst;
        e = e > 0.f ? e : NEG_SLOPE * e;
        float a = __expf(e - mx) * inv;
        uint2 hv = *(const uint2*)&h1b[(size_t)src * C1 + lane * 4];
        acc.x += a * b2f_lo(hv.x);
        acc.y += a * b2f_hi(hv.x);
        acc.z += a * b2f_lo(hv.y);
        acc.w += a * b2f_hi(hv.y);
    }
    int cb = lane * 4;
    float v0 = acc.x + b1[cb + 0];
    float v1 = acc.y + b1[cb + 1];
    float v2 = acc.z + b1[cb + 2];
    float v3 = acc.w + b1[cb + 3];
    v0 = v0 > 0.f ? v0 : (__expf(v0) - 1.f);
    v1 = v1 > 0.f ? v1 : (__expf(v1) - 1.f);
    v2 = v2 > 0.f ? v2 : (__expf(v2) - 1.f);
    v3 = v3 > 0.f ? v3 : (__expf(v3) - 1.f);
    *(float4*)&out1[(size_t)d * C1 + cb] = make_float4(v0, v1, v2, v3);
}

// ---------------- layer-2 GEMM (K=256 -> 16) fused with scores -------------
__global__ __launch_bounds__(256) void gemm2_scores_kernel(const float* __restrict__ out1,
                                                           const float* __restrict__ W2,
                                                           const float* __restrict__ a_src2,
                                                           const float* __restrict__ a_dst2,
                                                           float* __restrict__ h2,
                                                           float* __restrict__ s_src2,
                                                           float* __restrict__ s_dst2) {
    int tid = threadIdx.x;
    int n = blockIdx.x * 16 + (tid >> 4);
    int c = tid & 15;
    if (n >= NN) return;
    const float* row = out1 + (size_t)n * C1;
    float acc = 0.f;
#pragma unroll 8
    for (int k = 0; k < C1; ++k) acc += row[k] * W2[k * OUT_CH + c];
    h2[(size_t)n * OUT_CH + c] = acc;
    float ps = acc * a_src2[c];
    float pd = acc * a_dst2[c];
#pragma unroll
    for (int o = 1; o < 16; o <<= 1) {
        ps += __shfl_xor(ps, o);
        pd += __shfl_xor(pd, o);
    }
    if (c == 0) {
        s_src2[n] = ps;
        s_dst2[n] = pd;
    }
}

// ---------------- layer-2 softmax (online) + aggregate + bias --------------
__global__ __launch_bounds__(256) void agg2_kernel(const float* __restrict__ h2,
                                                   const float* __restrict__ s_src2,
                                                   const float* __restrict__ s_dst2,
                                                   const int* __restrict__ row_start,
                                                   const int* __restrict__ srcs,
                                                   const float* __restrict__ b2,
                                                   float* __restrict__ out) {
    int d = blockIdx.x * 4 + (threadIdx.x >> 6);
    if (d >= NN) return;
    int lane = threadIdx.x & 63;
    int start = row_start[d], end = row_start[d + 1];
    float sdst = s_dst2[d];

    float mx = -3.4e38f, ssum = 0.f;
    for (int i = start + lane; i < end; i += 64) {
        int src = srcs[i];
        float e = s_src2[src] + sdst;
        e = e > 0.f ? e : NEG_SLOPE * e;
        float m2 = fmaxf(mx, e);
        ssum = ssum * __expf(mx - m2) + __expf(e - m2);
        mx = m2;
    }
#pragma unroll
    for (int o = 1; o < 64; o <<= 1) {
        float mo = __shfl_xor(mx, o);
        float so = __shfl_xor(ssum, o);
        float m2 = fmaxf(mx, mo);
        ssum = ssum * __expf(mx - m2) + so * __expf(mo - m2);
        mx = m2;
    }
    float inv = 1.f / (ssum + EPS_SM);

    int j = lane >> 4;   // edge slot 0..3
    int c = lane & 15;   // channel
    float acc = 0.f;
    for (int i = start + j; i < end; i += 4) {
        int src = srcs[i];
        float e = s_src2[src] + sdst;
        e = e > 0.f ? e : NEG_SLOPE * e;
        float a = __expf(e - mx) * inv;
        acc += a * h2[(size_t)src * OUT_CH + c];
    }
    acc += __shfl_xor(acc, 16);
    acc += __shfl_xor(acc, 32);
    if (lane < 16) out[(size_t)d * OUT_CH + c] = acc + b2[c];
}

extern "C" void kernel_launch(void* const* d_in, const int* in_sizes, int n_in,
                              void* d_out, int out_size, void* d_ws, size_t ws_size,
                              hipStream_t stream) {
    const float* x      = (const float*)d_in[0];
    const int*   ei     = (const int*)d_in[1];
    const float* W1     = (const float*)d_in[2];
    const float* a_src1 = (const float*)d_in[3];
    const float* a_dst1 = (const float*)d_in[4];
    const float* b1     = (const float*)d_in[5];
    const float* W2     = (const float*)d_in[6];
    const float* a_src2 = (const float*)d_in[7];
    const float* a_dst2 = (const float*)d_in[8];
    const float* b2     = (const float*)d_in[9];
    float* out = (float*)d_out;

    const int E = in_sizes[1] / 2;
    const int Etot = E + NN;
    const int* src_arr = ei;
    const int* dst_arr = ei + E;

    // ---- carve workspace ----
    size_t off = 0;
    auto carve = [&](size_t bytes) -> void* {
        void* r = (char*)d_ws + off;
        off += (bytes + 255) & ~(size_t)255;
        return r;
    };
    unsigned short* h1b = (unsigned short*)carve((size_t)NN * C1 * 2);
    float* out1  = (float*)carve((size_t)NN * C1 * 4);
    float* ssrc1 = (float*)carve((size_t)NN * HEADS * 4);
    float* sdst1 = (float*)carve((size_t)NN * HEADS * 4);
    float* h2    = (float*)carve((size_t)NN * OUT_CH * 4);
    float* ssrc2 = (float*)carve((size_t)NN * 4);
    float* sdst2 = (float*)carve((size_t)NN * 4);
    int* deg     = (int*)carve((size_t)NN * 4);
    int* rowst   = (int*)carve((size_t)(NN + 1) * 4);
    int* cursor  = (int*)carve((size_t)NN * 4);
    int* srcs    = (int*)carve((size_t)Etot * 4);
    int* bsum    = (int*)carve(64 * 4);

    const int NB = (NN + SCAN_CHUNK - 1) / SCAN_CHUNK;   // 49

    // ---- CSR build ----
    hipMemsetAsync(deg, 0, (size_t)NN * 4, stream);
    hist_kernel<<<1024, 256, 0, stream>>>(dst_arr, deg, Etot, E);
    scan_blk_kernel<<<NB, 256, 0, stream>>>(deg, rowst, bsum, NN);
    scan_bsum_kernel<<<1, 64, 0, stream>>>(bsum, NB, rowst, NN, Etot);
    scan_add_kernel<<<NB, 256, 0, stream>>>(bsum, rowst, cursor, NN);
    scatter_kernel<<<1024, 256, 0, stream>>>(src_arr, dst_arr, cursor, srcs, Etot, E);

    // ---- layer 1 ----
    dim3 g1(C1 / BN, (NN + BM - 1) / BM);
    gemm1_kernel<<<g1, 256, 0, stream>>>(x, W1, h1b, NN, IN_CH, C1);
    scores1_kernel<<<NN, 256, 0, stream>>>(h1b, a_src1, a_dst1, ssrc1, sdst1);
    agg1_kernel<<<(NN + 3) / 4, 256, 0, stream>>>(h1b, ssrc1, sdst1, rowst, srcs, b1, out1);

    // ---- layer 2 ----
    gemm2_scores_kernel<<<(NN + 15) / 16, 256, 0, stream>>>(out1, W2, a_src2, a_dst2,
                                                            h2, ssrc2, sdst2);
    agg2_kernel<<<(NN + 3) / 4, 256, 0, stream>>>(h2, ssrc2, sdst2, rowst, srcs, b2, out);
}

// Round 3
// 336.334 us; speedup vs baseline: 1.6171x; 1.1315x over previous
//
#include <hip/hip_runtime.h>
#include <cstdint>
#include <cstddef>

#define NN 50000
#define IN_CH 128
#define C1 256        // HEADS*HID
#define HID 64
#define HEADS 4
#define OUT_CH 16
#define NEG_SLOPE 0.2f
#define EPS_SM 1e-16f
#define NEGINF -3.4e38f

typedef __attribute__((ext_vector_type(8))) short bf16x8;
typedef __attribute__((ext_vector_type(4))) float f32x4;

__device__ __forceinline__ unsigned short f2b(float f) {
    unsigned int u = __float_as_uint(f);
    u += 0x7fffu + ((u >> 16) & 1u);   // round-to-nearest-even
    return (unsigned short)(u >> 16);
}
__device__ __forceinline__ float b2f_lo(unsigned int packed) {
    return __uint_as_float(packed << 16);
}
__device__ __forceinline__ float b2f_hi(unsigned int packed) {
    return __uint_as_float(packed & 0xffff0000u);
}
__device__ __forceinline__ float bsf(short s) {
    return __uint_as_float(((unsigned int)(unsigned short)s) << 16);
}

// ---------------- weight prep: w1t[n][k] bf16, w2t[c][k] fp32 --------------
__global__ void cvt_weights(const float* __restrict__ W1, const float* __restrict__ W2,
                            unsigned short* __restrict__ w1t, float* __restrict__ w2t) {
    int b = blockIdx.x, t = threadIdx.x;
    if (b < 128) {
        // W1 row k=b: read W1[b][t] coalesced, write w1t[t][b]
        w1t[t * 128 + b] = f2b(W1[b * 256 + t]);
    } else {
        int k = (b - 128) * 16 + (t >> 4);
        int c = t & 15;
        w2t[c * 256 + k] = W2[k * 16 + c];
    }
}

// ---------------- GEMM1 (MFMA bf16): h1b[N,256] = x[N,128] @ W1 ------------
__global__ __launch_bounds__(256) void gemm1_mfma(const float* __restrict__ X,
                                                  const unsigned short* __restrict__ w1t,
                                                  unsigned short* __restrict__ h1b, int M) {
    __shared__ unsigned short xb[64 * 128];    // 16KB, swizzled
    __shared__ unsigned short wt[256 * 128];   // 64KB, swizzled (w1t staged)
    int tid = threadIdx.x;
    int m0 = blockIdx.x * 64;
    // stage w1t -> LDS (swizzled), 64KB
    {
        const uint4* gp = (const uint4*)w1t;
#pragma unroll
        for (int r = 0; r < 16; ++r) {
            int idx = r * 256 + tid;
            int byte = idx * 16;
            int row = byte >> 8;
            int cb = byte & 255;
            uint4 v = gp[idx];
            *(uint4*)((char*)wt + row * 256 + (cb ^ ((row & 7) << 4))) = v;
        }
    }
    // stage x tile -> bf16 LDS (swizzled)
    {
#pragma unroll
        for (int r = 0; r < 8; ++r) {
            int f = r * 256 + tid;   // float4 index
            int e = f * 4;
            int row = e >> 7, col = e & 127;
            float4 v = make_float4(0.f, 0.f, 0.f, 0.f);
            if (m0 + row < M) v = *(const float4*)&X[(size_t)(m0 + row) * 128 + col];
            ushort4 bb;
            bb.x = f2b(v.x); bb.y = f2b(v.y); bb.z = f2b(v.z); bb.w = f2b(v.w);
            *(ushort4*)((char*)xb + row * 256 + ((col * 2) ^ ((row & 7) << 4))) = bb;
        }
    }
    __syncthreads();
    int wv = tid >> 6, l = tid & 63;
    int lm = l & 15, lk = l >> 4;
    int swz = (lm & 7) << 4;
    f32x4 acc[4][4];
#pragma unroll
    for (int a = 0; a < 4; ++a)
#pragma unroll
        for (int b = 0; b < 4; ++b) acc[a][b] = (f32x4){0.f, 0.f, 0.f, 0.f};
#pragma unroll
    for (int kk = 0; kk < 4; ++kk) {
        int kb = (kk * 64 + lk * 16) ^ swz;
        bf16x8 af[4], bf[4];
#pragma unroll
        for (int mf = 0; mf < 4; ++mf)
            af[mf] = *(const bf16x8*)((const char*)xb + (mf * 16 + lm) * 256 + kb);
#pragma unroll
        for (int nt = 0; nt < 4; ++nt)
            bf[nt] = *(const bf16x8*)((const char*)wt + (wv * 64 + nt * 16 + lm) * 256 + kb);
#pragma unroll
        for (int mf = 0; mf < 4; ++mf)
#pragma unroll
            for (int nt = 0; nt < 4; ++nt)
                acc[mf][nt] = __builtin_amdgcn_mfma_f32_16x16x32_bf16(af[mf], bf[nt], acc[mf][nt], 0, 0, 0);
    }
#pragma unroll
    for (int mf = 0; mf < 4; ++mf) {
#pragma unroll
        for (int r = 0; r < 4; ++r) {
            int row = m0 + mf * 16 + lk * 4 + r;
            if (row < M) {
#pragma unroll
                for (int nt = 0; nt < 4; ++nt)
                    h1b[(size_t)row * 256 + wv * 64 + nt * 16 + lm] = f2b(acc[mf][nt][r]);
            }
        }
    }
}

// ---------------- scores1 (wave per node) ----------------------------------
__global__ __launch_bounds__(256) void scores1_kernel(const unsigned short* __restrict__ h1b,
                                                      const float* __restrict__ a_src,
                                                      const float* __restrict__ a_dst,
                                                      float* __restrict__ s_src,
                                                      float* __restrict__ s_dst) {
    int n = blockIdx.x * 4 + (threadIdx.x >> 6);
    int l = threadIdx.x & 63;
    int h = l >> 4;
    uint2 hv = *(const uint2*)&h1b[(size_t)n * C1 + l * 4];
    float4 av = *(const float4*)&a_src[l * 4];
    float4 dv = *(const float4*)&a_dst[l * 4];
    float x0 = b2f_lo(hv.x), x1 = b2f_hi(hv.x), x2 = b2f_lo(hv.y), x3 = b2f_hi(hv.y);
    float ps = x0 * av.x + x1 * av.y + x2 * av.z + x3 * av.w;
    float pd = x0 * dv.x + x1 * dv.y + x2 * dv.z + x3 * dv.w;
#pragma unroll
    for (int o = 1; o < 16; o <<= 1) {
        ps += __shfl_xor(ps, o);
        pd += __shfl_xor(pd, o);
    }
    if ((l & 15) == 0) {
        s_src[n * HEADS + h] = ps;
        s_dst[n * HEADS + h] = pd;
    }
}

// ---------------- CSR build ----------------
__global__ void hist_kernel(const int* __restrict__ dst_arr, int* __restrict__ deg,
                            int Etot, int E) {
    for (int i = blockIdx.x * blockDim.x + threadIdx.x; i < Etot; i += gridDim.x * blockDim.x) {
        int dst = (i < E) ? dst_arr[i] : (i - E);
        atomicAdd(&deg[dst], 1);
    }
}

#define SCAN_CHUNK 1024
__global__ __launch_bounds__(256) void scan_blk_kernel(const int* __restrict__ deg,
                                                       int* __restrict__ partial,
                                                       int* __restrict__ bsum, int n) {
    __shared__ int s[256];
    int t = threadIdx.x;
    int idx = blockIdx.x * SCAN_CHUNK + t * 4;
    int4 v = make_int4(0, 0, 0, 0);
    if (idx + 3 < n) v = *(const int4*)&deg[idx];
    else {
        if (idx < n) v.x = deg[idx];
        if (idx + 1 < n) v.y = deg[idx + 1];
        if (idx + 2 < n) v.z = deg[idx + 2];
    }
    int t1 = v.x, t2 = t1 + v.y, t3 = t2 + v.z, t4 = t3 + v.w;
    s[t] = t4;
    __syncthreads();
    for (int off = 1; off < 256; off <<= 1) {
        int x = (t >= off) ? s[t - off] : 0;
        __syncthreads();
        s[t] += x;
        __syncthreads();
    }
    int excl = s[t] - t4;
    if (t == 255) bsum[blockIdx.x] = s[255];
    if (idx < n) partial[idx] = excl;
    if (idx + 1 < n) partial[idx + 1] = excl + t1;
    if (idx + 2 < n) partial[idx + 2] = excl + t2;
    if (idx + 3 < n) partial[idx + 3] = excl + t3;
}

__global__ void scan_bsum_kernel(int* __restrict__ bsum, int nb,
                                 int* __restrict__ row_start, int n, int total) {
    int t = threadIdx.x;   // 64 threads
    int v = (t < nb) ? bsum[t] : 0;
    int own = v;
#pragma unroll
    for (int off = 1; off < 64; off <<= 1) {
        int x = __shfl_up(v, off);
        if (t >= off) v += x;
    }
    if (t < nb) bsum[t] = v - own;
    if (t == 0) row_start[n] = total;
}

__global__ __launch_bounds__(256) void scan_add_kernel(const int* __restrict__ bsum,
                                                       int* __restrict__ row_start,
                                                       int* __restrict__ cursor, int n) {
    int base = blockIdx.x * SCAN_CHUNK;
    int off = bsum[blockIdx.x];
    for (int j = threadIdx.x; j < SCAN_CHUNK; j += 256) {
        int i = base + j;
        if (i < n) {
            int r = row_start[i] + off;
            row_start[i] = r;
            cursor[i] = r;
        }
    }
}

__global__ void scatter_kernel(const int* __restrict__ src_arr, const int* __restrict__ dst_arr,
                               int* __restrict__ cursor, int* __restrict__ srcs,
                               int Etot, int E) {
    for (int i = blockIdx.x * blockDim.x + threadIdx.x; i < Etot; i += gridDim.x * blockDim.x) {
        int dst, src;
        if (i < E) { dst = dst_arr[i]; src = src_arr[i]; }
        else { dst = i - E; src = i - E; }
        int pos = atomicAdd(&cursor[dst], 1);
        srcs[pos] = src;
    }
}

// ---------------- layer-1 alpha precompute ---------------------------------
__global__ __launch_bounds__(256) void agg1a_kernel(const float* __restrict__ ssrc1,
                                                    const float* __restrict__ sdst1,
                                                    const int* __restrict__ row_start,
                                                    const int* __restrict__ srcs,
                                                    float* __restrict__ alpha1) {
    int d = blockIdx.x * 4 + (threadIdx.x >> 6);
    int l = threadIdx.x & 63;
    int sub = l & 15, h = l >> 4;
    int start = row_start[d], end = row_start[d + 1];
    float sdst = sdst1[d * HEADS + h];
    float e0 = NEGINF, e1 = NEGINF, e2 = NEGINF, e3 = NEGINF;
    int i0 = start + sub;
    auto comp = [&](int i) -> float {
        int s = srcs[i];
        float e = ssrc1[s * HEADS + h] + sdst;
        return e > 0.f ? e : NEG_SLOPE * e;
    };
    if (i0 < end) e0 = comp(i0);
    if (i0 + 16 < end) e1 = comp(i0 + 16);
    if (i0 + 32 < end) e2 = comp(i0 + 32);
    if (i0 + 48 < end) e3 = comp(i0 + 48);
    float mx = fmaxf(fmaxf(e0, e1), fmaxf(e2, e3));
    for (int i = i0 + 64; i < end; i += 16) mx = fmaxf(mx, comp(i));   // rare
#pragma unroll
    for (int o = 1; o < 16; o <<= 1) mx = fmaxf(mx, __shfl_xor(mx, o));
    float s0 = __expf(e0 - mx), s1 = __expf(e1 - mx);
    float s2 = __expf(e2 - mx), s3 = __expf(e3 - mx);
    float ssum = s0 + s1 + s2 + s3;
    for (int i = i0 + 64; i < end; i += 16) ssum += __expf(comp(i) - mx);
#pragma unroll
    for (int o = 1; o < 16; o <<= 1) ssum += __shfl_xor(ssum, o);
    float inv = 1.f / (ssum + EPS_SM);
    if (i0 < end) alpha1[i0 * 4 + h] = s0 * inv;
    if (i0 + 16 < end) alpha1[(i0 + 16) * 4 + h] = s1 * inv;
    if (i0 + 32 < end) alpha1[(i0 + 32) * 4 + h] = s2 * inv;
    if (i0 + 48 < end) alpha1[(i0 + 48) * 4 + h] = s3 * inv;
    for (int i = i0 + 64; i < end; i += 16) alpha1[i * 4 + h] = __expf(comp(i) - mx) * inv;
}

// ---------------- layer-1 aggregate + bias + ELU + bf16 store --------------
__global__ __launch_bounds__(256) void agg1b_kernel(const unsigned short* __restrict__ h1b,
                                                    const float* __restrict__ alpha1,
                                                    const int* __restrict__ row_start,
                                                    const int* __restrict__ srcs,
                                                    const float* __restrict__ b1,
                                                    unsigned short* __restrict__ out1b) {
    int d = blockIdx.x * 4 + (threadIdx.x >> 6);
    int l = threadIdx.x & 63;
    int h = l >> 4;
    int start = row_start[d], end = row_start[d + 1];
    float4 acc = make_float4(0.f, 0.f, 0.f, 0.f);
    int i = start;
    for (; i + 4 <= end; i += 4) {
        int sA = srcs[i], sB = srcs[i + 1], sC = srcs[i + 2], sD = srcs[i + 3];
        float aA = alpha1[i * 4 + h], aB = alpha1[(i + 1) * 4 + h];
        float aC = alpha1[(i + 2) * 4 + h], aD = alpha1[(i + 3) * 4 + h];
        uint2 vA = *(const uint2*)&h1b[(size_t)sA * C1 + l * 4];
        uint2 vB = *(const uint2*)&h1b[(size_t)sB * C1 + l * 4];
        uint2 vC = *(const uint2*)&h1b[(size_t)sC * C1 + l * 4];
        uint2 vD = *(const uint2*)&h1b[(size_t)sD * C1 + l * 4];
        acc.x += aA * b2f_lo(vA.x) + aB * b2f_lo(vB.x) + aC * b2f_lo(vC.x) + aD * b2f_lo(vD.x);
        acc.y += aA * b2f_hi(vA.x) + aB * b2f_hi(vB.x) + aC * b2f_hi(vC.x) + aD * b2f_hi(vD.x);
        acc.z += aA * b2f_lo(vA.y) + aB * b2f_lo(vB.y) + aC * b2f_lo(vC.y) + aD * b2f_lo(vD.y);
        acc.w += aA * b2f_hi(vA.y) + aB * b2f_hi(vB.y) + aC * b2f_hi(vC.y) + aD * b2f_hi(vD.y);
    }
    for (; i < end; ++i) {
        int s = srcs[i];
        float a = alpha1[i * 4 + h];
        uint2 v = *(const uint2*)&h1b[(size_t)s * C1 + l * 4];
        acc.x += a * b2f_lo(v.x);
        acc.y += a * b2f_hi(v.x);
        acc.z += a * b2f_lo(v.y);
        acc.w += a * b2f_hi(v.y);
    }
    int cb = l * 4;
    float4 bb = *(const float4*)&b1[cb];
    float v0 = acc.x + bb.x, v1 = acc.y + bb.y, v2 = acc.z + bb.z, v3 = acc.w + bb.w;
    v0 = v0 > 0.f ? v0 : (__expf(v0) - 1.f);
    v1 = v1 > 0.f ? v1 : (__expf(v1) - 1.f);
    v2 = v2 > 0.f ? v2 : (__expf(v2) - 1.f);
    v3 = v3 > 0.f ? v3 : (__expf(v3) - 1.f);
    ushort4 o;
    o.x = f2b(v0); o.y = f2b(v1); o.z = f2b(v2); o.w = f2b(v3);
    *(ushort4*)&out1b[(size_t)d * C1 + cb] = o;
}

// ---------------- layer-2 GEMM (bf16 in, K=256 -> 16) + scores -------------
__global__ __launch_bounds__(256) void gemm2_scores_kernel(const unsigned short* __restrict__ out1b,
                                                           const float* __restrict__ w2t,
                                                           const float* __restrict__ a_src2,
                                                           const float* __restrict__ a_dst2,
                                                           float* __restrict__ h2,
                                                           float* __restrict__ ssrc2,
                                                           float* __restrict__ sdst2) {
    __shared__ unsigned short srow[16 * 264];   // stride 264 shorts = 528B (bank-skewed)
    int tid = threadIdx.x;
    int nb0 = blockIdx.x * 16;
    {
        const uint4* gp = (const uint4*)(out1b + (size_t)nb0 * C1);
        int idx = tid * 2;
        uint4 v0 = gp[idx], v1 = gp[idx + 1];
        int row = tid >> 4;
        int cb = (tid & 15) * 32;
        *(uint4*)((char*)srow + row * 528 + cb) = v0;
        *(uint4*)((char*)srow + row * 528 + cb + 16) = v1;
    }
    __syncthreads();
    int r = tid >> 4, c = tid & 15;
    const char* rp = (const char*)srow + r * 528;
    const float* wrow = w2t + c * 256;
    float acc = 0.f;
#pragma unroll
    for (int k8 = 0; k8 < 32; ++k8) {
        bf16x8 hv = *(const bf16x8*)(rp + k8 * 16);
        float4 wa = *(const float4*)&wrow[k8 * 8];
        float4 wb = *(const float4*)&wrow[k8 * 8 + 4];
        acc += bsf(hv[0]) * wa.x + bsf(hv[1]) * wa.y + bsf(hv[2]) * wa.z + bsf(hv[3]) * wa.w;
        acc += bsf(hv[4]) * wb.x + bsf(hv[5]) * wb.y + bsf(hv[6]) * wb.z + bsf(hv[7]) * wb.w;
    }
    int n = nb0 + r;
    h2[(size_t)n * OUT_CH + c] = acc;
    float ps = acc * a_src2[c];
    float pd = acc * a_dst2[c];
#pragma unroll
    for (int o = 1; o < 16; o <<= 1) {
        ps += __shfl_xor(ps, o);
        pd += __shfl_xor(pd, o);
    }
    if (c == 0) {
        ssrc2[n] = ps;
        sdst2[n] = pd;
    }
}

// ---------------- layer-2 alpha precompute ---------------------------------
__global__ __launch_bounds__(256) void agg2a_kernel(const float* __restrict__ ssrc2,
                                                    const float* __restrict__ sdst2,
                                                    const int* __restrict__ row_start,
                                                    const int* __restrict__ srcs,
                                                    float* __restrict__ alpha2) {
    int d = blockIdx.x * 4 + (threadIdx.x >> 6);
    int l = threadIdx.x & 63;
    int start = row_start[d], end = row_start[d + 1];
    float sdst = sdst2[d];
    auto comp = [&](int i) -> float {
        int s = srcs[i];
        float e = ssrc2[s] + sdst;
        return e > 0.f ? e : NEG_SLOPE * e;
    };
    float e0 = NEGINF, e1 = NEGINF;
    int i0 = start + l;
    if (i0 < end) e0 = comp(i0);
    if (i0 + 64 < end) e1 = comp(i0 + 64);
    float mx = fmaxf(e0, e1);
    for (int i = i0 + 128; i < end; i += 64) mx = fmaxf(mx, comp(i));
#pragma unroll
    for (int o = 1; o < 64; o <<= 1) mx = fmaxf(mx, __shfl_xor(mx, o));
    float s0 = __expf(e0 - mx), s1 = __expf(e1 - mx);
    float ssum = s0 + s1;
    for (int i = i0 + 128; i < end; i += 64) ssum += __expf(comp(i) - mx);
#pragma unroll
    for (int o = 1; o < 64; o <<= 1) ssum += __shfl_xor(ssum, o);
    float inv = 1.f / (ssum + EPS_SM);
    if (i0 < end) alpha2[i0] = s0 * inv;
    if (i0 + 64 < end) alpha2[i0 + 64] = s1 * inv;
    for (int i = i0 + 128; i < end; i += 64) alpha2[i] = __expf(comp(i) - mx) * inv;
}

// ---------------- layer-2 aggregate + bias ---------------------------------
__global__ __launch_bounds__(256) void agg2b_kernel(const float* __restrict__ h2,
                                                    const float* __restrict__ alpha2,
                                                    const int* __restrict__ row_start,
                                                    const int* __restrict__ srcs,
                                                    const float* __restrict__ b2,
                                                    float* __restrict__ out) {
    int d = blockIdx.x * 4 + (threadIdx.x >> 6);
    int l = threadIdx.x & 63;
    int start = row_start[d], end = row_start[d + 1];
    int j = l >> 4, c = l & 15;
    float acc = 0.f;
    int i = start + j;
    for (; i + 4 < end; i += 8) {
        int sA = srcs[i], sB = srcs[i + 4];
        float aA = alpha2[i], aB = alpha2[i + 4];
        acc += aA * h2[(size_t)sA * OUT_CH + c] + aB * h2[(size_t)sB * OUT_CH + c];
    }
    for (; i < end; i += 4) {
        int s = srcs[i];
        acc += alpha2[i] * h2[(size_t)s * OUT_CH + c];
    }
    acc += __shfl_xor(acc, 16);
    acc += __shfl_xor(acc, 32);
    if (l < 16) out[(size_t)d * OUT_CH + c] = acc + b2[c];
}

extern "C" void kernel_launch(void* const* d_in, const int* in_sizes, int n_in,
                              void* d_out, int out_size, void* d_ws, size_t ws_size,
                              hipStream_t stream) {
    const float* x      = (const float*)d_in[0];
    const int*   ei     = (const int*)d_in[1];
    const float* W1     = (const float*)d_in[2];
    const float* a_src1 = (const float*)d_in[3];
    const float* a_dst1 = (const float*)d_in[4];
    const float* b1     = (const float*)d_in[5];
    const float* W2     = (const float*)d_in[6];
    const float* a_src2 = (const float*)d_in[7];
    const float* a_dst2 = (const float*)d_in[8];
    const float* b2     = (const float*)d_in[9];
    float* out = (float*)d_out;

    const int E = in_sizes[1] / 2;
    const int Etot = E + NN;
    const int* src_arr = ei;
    const int* dst_arr = ei + E;

    size_t off = 0;
    auto carve = [&](size_t bytes) -> void* {
        void* r = (char*)d_ws + off;
        off += (bytes + 255) & ~(size_t)255;
        return r;
    };
    unsigned short* h1b  = (unsigned short*)carve((size_t)NN * C1 * 2);
    unsigned short* out1b= (unsigned short*)carve((size_t)NN * C1 * 2);
    unsigned short* w1t  = (unsigned short*)carve((size_t)IN_CH * C1 * 2);
    float* w2t   = (float*)carve((size_t)C1 * OUT_CH * 4);
    float* ssrc1 = (float*)carve((size_t)NN * HEADS * 4);
    float* sdst1 = (float*)carve((size_t)NN * HEADS * 4);
    float* h2    = (float*)carve((size_t)NN * OUT_CH * 4);
    float* ssrc2 = (float*)carve((size_t)NN * 4);
    float* sdst2 = (float*)carve((size_t)NN * 4);
    float* alpha1= (float*)carve((size_t)Etot * HEADS * 4);
    float* alpha2= (float*)carve((size_t)Etot * 4);
    int* deg     = (int*)carve((size_t)NN * 4);
    int* rowst   = (int*)carve((size_t)(NN + 1) * 4);
    int* cursor  = (int*)carve((size_t)NN * 4);
    int* srcs    = (int*)carve((size_t)Etot * 4);
    int* bsum    = (int*)carve(64 * 4);

    const int NB = (NN + SCAN_CHUNK - 1) / SCAN_CHUNK;   // 49

    // ---- CSR build ----
    hipMemsetAsync(deg, 0, (size_t)NN * 4, stream);
    hist_kernel<<<1024, 256, 0, stream>>>(dst_arr, deg, Etot, E);
    scan_blk_kernel<<<NB, 256, 0, stream>>>(deg, rowst, bsum, NN);
    scan_bsum_kernel<<<1, 64, 0, stream>>>(bsum, NB, rowst, NN, Etot);
    scan_add_kernel<<<NB, 256, 0, stream>>>(bsum, rowst, cursor, NN);
    scatter_kernel<<<1024, 256, 0, stream>>>(src_arr, dst_arr, cursor, srcs, Etot, E);

    // ---- weights prep ----
    cvt_weights<<<144, 256, 0, stream>>>(W1, W2, w1t, w2t);

    // ---- layer 1 ----
    gemm1_mfma<<<(NN + 63) / 64, 256, 0, stream>>>(x, w1t, h1b, NN);
    scores1_kernel<<<NN / 4, 256, 0, stream>>>(h1b, a_src1, a_dst1, ssrc1, sdst1);
    agg1a_kernel<<<NN / 4, 256, 0, stream>>>(ssrc1, sdst1, rowst, srcs, alpha1);
    agg1b_kernel<<<NN / 4, 256, 0, stream>>>(h1b, alpha1, rowst, srcs, b1, out1b);

    // ---- layer 2 ----
    gemm2_scores_kernel<<<NN / 16, 256, 0, stream>>>(out1b, w2t, a_src2, a_dst2,
                                                     h2, ssrc2, sdst2);
    agg2a_kernel<<<NN / 4, 256, 0, stream>>>(ssrc2, sdst2, rowst, srcs, alpha2);
    agg2b_kernel<<<NN / 4, 256, 0, stream>>>(h2, alpha2, rowst, srcs, b2, out);
}

// Round 4
// 263.210 us; speedup vs baseline: 2.0664x; 1.2778x over previous
//
#include <hip/hip_runtime.h>
#include <cstdint>
#include <cstddef>

#define NN 50000
#define IN_CH 128
#define C1 256        // HEADS*HID
#define HID 64
#define HEADS 4
#define OUT_CH 16
#define NEG_SLOPE 0.2f
#define EPS_SM 1e-16f
#define NEGINF -3.4e38f

typedef __attribute__((ext_vector_type(8))) short bf16x8;
typedef __attribute__((ext_vector_type(4))) float f32x4;

__device__ __forceinline__ unsigned short f2b(float f) {
    unsigned int u = __float_as_uint(f);
    u += 0x7fffu + ((u >> 16) & 1u);   // round-to-nearest-even
    return (unsigned short)(u >> 16);
}
__device__ __forceinline__ float b2f_lo(unsigned int packed) {
    return __uint_as_float(packed << 16);
}
__device__ __forceinline__ float b2f_hi(unsigned int packed) {
    return __uint_as_float(packed & 0xffff0000u);
}

// -------- weight prep: w1t[n][k] bf16 (n-major), w2b[c][k] bf16 ------------
__global__ void cvt_weights(const float* __restrict__ W1, const float* __restrict__ W2,
                            unsigned short* __restrict__ w1t, unsigned short* __restrict__ w2b) {
    int b = blockIdx.x, t = threadIdx.x;
    if (b < 128) {
        w1t[t * 128 + b] = f2b(W1[b * 256 + t]);
    } else {
        int k = (b - 128) * 16 + (t >> 4);
        int c = t & 15;
        w2b[c * 256 + k] = f2b(W2[k * 16 + c]);
    }
}

// ---------------- GEMM1 (MFMA bf16): h1b[N,256] = x[N,128] @ W1 ------------
__global__ __launch_bounds__(256) void gemm1_mfma(const float* __restrict__ X,
                                                  const unsigned short* __restrict__ w1t,
                                                  unsigned short* __restrict__ h1b, int M) {
    __shared__ unsigned short xb[64 * 128];    // 16KB, swizzled
    __shared__ unsigned short wt[256 * 128];   // 64KB, swizzled (w1t staged)
    int tid = threadIdx.x;
    int m0 = blockIdx.x * 64;
    {
        const uint4* gp = (const uint4*)w1t;
#pragma unroll
        for (int r = 0; r < 16; ++r) {
            int idx = r * 256 + tid;
            int byte = idx * 16;
            int row = byte >> 8;
            int cb = byte & 255;
            uint4 v = gp[idx];
            *(uint4*)((char*)wt + row * 256 + (cb ^ ((row & 7) << 4))) = v;
        }
    }
    {
#pragma unroll
        for (int r = 0; r < 8; ++r) {
            int f = r * 256 + tid;   // float4 index
            int e = f * 4;
            int row = e >> 7, col = e & 127;
            float4 v = make_float4(0.f, 0.f, 0.f, 0.f);
            if (m0 + row < M) v = *(const float4*)&X[(size_t)(m0 + row) * 128 + col];
            ushort4 bb;
            bb.x = f2b(v.x); bb.y = f2b(v.y); bb.z = f2b(v.z); bb.w = f2b(v.w);
            *(ushort4*)((char*)xb + row * 256 + ((col * 2) ^ ((row & 7) << 4))) = bb;
        }
    }
    __syncthreads();
    int wv = tid >> 6, l = tid & 63;
    int lm = l & 15, lk = l >> 4;
    int swz = (lm & 7) << 4;
    f32x4 acc[4][4];
#pragma unroll
    for (int a = 0; a < 4; ++a)
#pragma unroll
        for (int b = 0; b < 4; ++b) acc[a][b] = (f32x4){0.f, 0.f, 0.f, 0.f};
#pragma unroll
    for (int kk = 0; kk < 4; ++kk) {
        int kb = (kk * 64 + lk * 16) ^ swz;
        bf16x8 af[4], bfr[4];
#pragma unroll
        for (int mf = 0; mf < 4; ++mf)
            af[mf] = *(const bf16x8*)((const char*)xb + (mf * 16 + lm) * 256 + kb);
#pragma unroll
        for (int nt = 0; nt < 4; ++nt)
            bfr[nt] = *(const bf16x8*)((const char*)wt + (wv * 64 + nt * 16 + lm) * 256 + kb);
#pragma unroll
        for (int mf = 0; mf < 4; ++mf)
#pragma unroll
            for (int nt = 0; nt < 4; ++nt)
                acc[mf][nt] = __builtin_amdgcn_mfma_f32_16x16x32_bf16(af[mf], bfr[nt], acc[mf][nt], 0, 0, 0);
    }
#pragma unroll
    for (int mf = 0; mf < 4; ++mf) {
#pragma unroll
        for (int r = 0; r < 4; ++r) {
            int row = m0 + mf * 16 + lk * 4 + r;
            if (row < M) {
#pragma unroll
                for (int nt = 0; nt < 4; ++nt)
                    h1b[(size_t)row * 256 + wv * 64 + nt * 16 + lm] = f2b(acc[mf][nt][r]);
            }
        }
    }
}

// ---------------- scores1 (16 lanes per node) ------------------------------
__global__ __launch_bounds__(256) void scores1_kernel(const unsigned short* __restrict__ h1b,
                                                      const float* __restrict__ a_src,
                                                      const float* __restrict__ a_dst,
                                                      float* __restrict__ s_src,
                                                      float* __restrict__ s_dst) {
    int n = blockIdx.x * 4 + (threadIdx.x >> 6);
    int l = threadIdx.x & 63;
    int h = l >> 4;
    uint2 hv = *(const uint2*)&h1b[(size_t)n * C1 + l * 4];
    float4 av = *(const float4*)&a_src[l * 4];
    float4 dv = *(const float4*)&a_dst[l * 4];
    float x0 = b2f_lo(hv.x), x1 = b2f_hi(hv.x), x2 = b2f_lo(hv.y), x3 = b2f_hi(hv.y);
    float ps = x0 * av.x + x1 * av.y + x2 * av.z + x3 * av.w;
    float pd = x0 * dv.x + x1 * dv.y + x2 * dv.z + x3 * dv.w;
#pragma unroll
    for (int o = 1; o < 16; o <<= 1) {
        ps += __shfl_xor(ps, o);
        pd += __shfl_xor(pd, o);
    }
    if ((l & 15) == 0) {
        s_src[n * HEADS + h] = ps;
        s_dst[n * HEADS + h] = pd;
    }
}

// ---------------- CSR build ----------------
__global__ void hist_kernel(const int* __restrict__ dst_arr, int* __restrict__ deg,
                            int Etot, int E) {
    for (int i = blockIdx.x * blockDim.x + threadIdx.x; i < Etot; i += gridDim.x * blockDim.x) {
        int dst = (i < E) ? dst_arr[i] : (i - E);
        atomicAdd(&deg[dst], 1);
    }
}

#define SCAN_CHUNK 1024
__global__ __launch_bounds__(256) void scan_blk_kernel(const int* __restrict__ deg,
                                                       int* __restrict__ partial,
                                                       int* __restrict__ bsum, int n) {
    __shared__ int s[256];
    int t = threadIdx.x;
    int idx = blockIdx.x * SCAN_CHUNK + t * 4;
    int4 v = make_int4(0, 0, 0, 0);
    if (idx + 3 < n) v = *(const int4*)&deg[idx];
    else {
        if (idx < n) v.x = deg[idx];
        if (idx + 1 < n) v.y = deg[idx + 1];
        if (idx + 2 < n) v.z = deg[idx + 2];
    }
    int t1 = v.x, t2 = t1 + v.y, t3 = t2 + v.z, t4 = t3 + v.w;
    s[t] = t4;
    __syncthreads();
    for (int off = 1; off < 256; off <<= 1) {
        int x = (t >= off) ? s[t - off] : 0;
        __syncthreads();
        s[t] += x;
        __syncthreads();
    }
    int excl = s[t] - t4;
    if (t == 255) bsum[blockIdx.x] = s[255];
    if (idx < n) partial[idx] = excl;
    if (idx + 1 < n) partial[idx + 1] = excl + t1;
    if (idx + 2 < n) partial[idx + 2] = excl + t2;
    if (idx + 3 < n) partial[idx + 3] = excl + t3;
}

__global__ void scan_bsum_kernel(int* __restrict__ bsum, int nb,
                                 int* __restrict__ row_start, int n, int total) {
    int t = threadIdx.x;   // 64 threads
    int v = (t < nb) ? bsum[t] : 0;
    int own = v;
#pragma unroll
    for (int off = 1; off < 64; off <<= 1) {
        int x = __shfl_up(v, off);
        if (t >= off) v += x;
    }
    if (t < nb) bsum[t] = v - own;
    if (t == 0) row_start[n] = total;
}

__global__ __launch_bounds__(256) void scan_add_kernel(const int* __restrict__ bsum,
                                                       int* __restrict__ row_start,
                                                       int* __restrict__ cursor, int n) {
    int base = blockIdx.x * SCAN_CHUNK;
    int off = bsum[blockIdx.x];
    for (int j = threadIdx.x; j < SCAN_CHUNK; j += 256) {
        int i = base + j;
        if (i < n) {
            int r = row_start[i] + off;
            row_start[i] = r;
            cursor[i] = r;
        }
    }
}

__global__ void scatter_kernel(const int* __restrict__ src_arr, const int* __restrict__ dst_arr,
                               int* __restrict__ cursor, int* __restrict__ srcs,
                               int Etot, int E) {
    for (int i = blockIdx.x * blockDim.x + threadIdx.x; i < Etot; i += gridDim.x * blockDim.x) {
        int dst, src;
        if (i < E) { dst = dst_arr[i]; src = src_arr[i]; }
        else { dst = i - E; src = i - E; }
        int pos = atomicAdd(&cursor[dst], 1);
        srcs[pos] = src;
    }
}

// ---------------- layer-1 alpha precompute ---------------------------------
__global__ __launch_bounds__(256) void agg1a_kernel(const float* __restrict__ ssrc1,
                                                    const float* __restrict__ sdst1,
                                                    const int* __restrict__ row_start,
                                                    const int* __restrict__ srcs,
                                                    float* __restrict__ alpha1) {
    int d = blockIdx.x * 4 + (threadIdx.x >> 6);
    int l = threadIdx.x & 63;
    int sub = l & 15, h = l >> 4;
    int start = row_start[d], end = row_start[d + 1];
    float sdst = sdst1[d * HEADS + h];
    float e0 = NEGINF, e1 = NEGINF, e2 = NEGINF, e3 = NEGINF;
    int i0 = start + sub;
    auto comp = [&](int i) -> float {
        int s = srcs[i];
        float e = ssrc1[s * HEADS + h] + sdst;
        return e > 0.f ? e : NEG_SLOPE * e;
    };
    if (i0 < end) e0 = comp(i0);
    if (i0 + 16 < end) e1 = comp(i0 + 16);
    if (i0 + 32 < end) e2 = comp(i0 + 32);
    if (i0 + 48 < end) e3 = comp(i0 + 48);
    float mx = fmaxf(fmaxf(e0, e1), fmaxf(e2, e3));
    for (int i = i0 + 64; i < end; i += 16) mx = fmaxf(mx, comp(i));   // rare
#pragma unroll
    for (int o = 1; o < 16; o <<= 1) mx = fmaxf(mx, __shfl_xor(mx, o));
    float s0 = __expf(e0 - mx), s1 = __expf(e1 - mx);
    float s2 = __expf(e2 - mx), s3 = __expf(e3 - mx);
    float ssum = s0 + s1 + s2 + s3;
    for (int i = i0 + 64; i < end; i += 16) ssum += __expf(comp(i) - mx);
#pragma unroll
    for (int o = 1; o < 16; o <<= 1) ssum += __shfl_xor(ssum, o);
    float inv = 1.f / (ssum + EPS_SM);
    if (i0 < end) alpha1[i0 * 4 + h] = s0 * inv;
    if (i0 + 16 < end) alpha1[(i0 + 16) * 4 + h] = s1 * inv;
    if (i0 + 32 < end) alpha1[(i0 + 32) * 4 + h] = s2 * inv;
    if (i0 + 48 < end) alpha1[(i0 + 48) * 4 + h] = s3 * inv;
    for (int i = i0 + 64; i < end; i += 16) alpha1[i * 4 + h] = __expf(comp(i) - mx) * inv;
}

// ---------------- layer-1 aggregate + bias + ELU + bf16 store --------------
__global__ __launch_bounds__(256) void agg1b_kernel(const unsigned short* __restrict__ h1b,
                                                    const float* __restrict__ alpha1,
                                                    const int* __restrict__ row_start,
                                                    const int* __restrict__ srcs,
                                                    const float* __restrict__ b1,
                                                    unsigned short* __restrict__ out1b) {
    int d = blockIdx.x * 4 + (threadIdx.x >> 6);
    int l = threadIdx.x & 63;
    int h = l >> 4;
    int start = row_start[d], end = row_start[d + 1];
    float4 acc = make_float4(0.f, 0.f, 0.f, 0.f);
    int i = start;
    for (; i + 4 <= end; i += 4) {
        int sA = srcs[i], sB = srcs[i + 1], sC = srcs[i + 2], sD = srcs[i + 3];
        float aA = alpha1[i * 4 + h], aB = alpha1[(i + 1) * 4 + h];
        float aC = alpha1[(i + 2) * 4 + h], aD = alpha1[(i + 3) * 4 + h];
        uint2 vA = *(const uint2*)&h1b[(size_t)sA * C1 + l * 4];
        uint2 vB = *(const uint2*)&h1b[(size_t)sB * C1 + l * 4];
        uint2 vC = *(const uint2*)&h1b[(size_t)sC * C1 + l * 4];
        uint2 vD = *(const uint2*)&h1b[(size_t)sD * C1 + l * 4];
        acc.x += aA * b2f_lo(vA.x) + aB * b2f_lo(vB.x) + aC * b2f_lo(vC.x) + aD * b2f_lo(vD.x);
        acc.y += aA * b2f_hi(vA.x) + aB * b2f_hi(vB.x) + aC * b2f_hi(vC.x) + aD * b2f_hi(vD.x);
        acc.z += aA * b2f_lo(vA.y) + aB * b2f_lo(vB.y) + aC * b2f_lo(vC.y) + aD * b2f_lo(vD.y);
        acc.w += aA * b2f_hi(vA.y) + aB * b2f_hi(vB.y) + aC * b2f_hi(vC.y) + aD * b2f_hi(vD.y);
    }
    for (; i < end; ++i) {
        int s = srcs[i];
        float a = alpha1[i * 4 + h];
        uint2 v = *(const uint2*)&h1b[(size_t)s * C1 + l * 4];
        acc.x += a * b2f_lo(v.x);
        acc.y += a * b2f_hi(v.x);
        acc.z += a * b2f_lo(v.y);
        acc.w += a * b2f_hi(v.y);
    }
    int cb = l * 4;
    float4 bb = *(const float4*)&b1[cb];
    float v0 = acc.x + bb.x, v1 = acc.y + bb.y, v2 = acc.z + bb.z, v3 = acc.w + bb.w;
    v0 = v0 > 0.f ? v0 : (__expf(v0) - 1.f);
    v1 = v1 > 0.f ? v1 : (__expf(v1) - 1.f);
    v2 = v2 > 0.f ? v2 : (__expf(v2) - 1.f);
    v3 = v3 > 0.f ? v3 : (__expf(v3) - 1.f);
    ushort4 o;
    o.x = f2b(v0); o.y = f2b(v1); o.z = f2b(v2); o.w = f2b(v3);
    *(ushort4*)&out1b[(size_t)d * C1 + cb] = o;
}

// ------- GEMM2 (MFMA): h2[N,16] = out1b[N,256] @ W2b  + fused scores -------
// 64 rows/block, 4 waves, 16 rows/wave. LDS rows padded to 528B (2-way bank
// aliasing only, free). B-fragments (8KB W2 bf16) live in registers.
__global__ __launch_bounds__(256) void gemm2_mfma(const unsigned short* __restrict__ out1b,
                                                  const unsigned short* __restrict__ w2b,
                                                  const float* __restrict__ a_src2,
                                                  const float* __restrict__ a_dst2,
                                                  float* __restrict__ h2,
                                                  float* __restrict__ ssrc2,
                                                  float* __restrict__ sdst2, int M) {
    __shared__ char ab[64 * 528];
    int tid = threadIdx.x;
    int m0 = blockIdx.x * 64;
    // stage 64 rows of out1b (bf16, 512B each) coalesced into padded LDS
#pragma unroll
    for (int r = 0; r < 8; ++r) {
        int byte = r * 4096 + tid * 16;
        int row = byte >> 9, col = byte & 511;
        uint4 v = make_uint4(0u, 0u, 0u, 0u);
        if (m0 + row < M)
            v = *(const uint4*)((const char*)out1b + (size_t)(m0 + row) * 512 + col);
        *(uint4*)(ab + row * 528 + col) = v;
    }
    int wv = tid >> 6, l = tid & 63;
    int lm = l & 15, lk = l >> 4;
    // B fragments in registers: lane holds B[k=(lk*8 + kk*32)..+8][col=lm]
    bf16x8 bfr[8];
#pragma unroll
    for (int kk = 0; kk < 8; ++kk)
        bfr[kk] = *(const bf16x8*)&w2b[lm * 256 + lk * 8 + kk * 32];
    __syncthreads();
    f32x4 acc = (f32x4){0.f, 0.f, 0.f, 0.f};
    const char* base = ab + (wv * 16 + lm) * 528 + lk * 16;
#pragma unroll
    for (int kk = 0; kk < 8; ++kk) {
        bf16x8 af = *(const bf16x8*)(base + kk * 64);
        acc = __builtin_amdgcn_mfma_f32_16x16x32_bf16(af, bfr[kk], acc, 0, 0, 0);
    }
    float asc = a_src2[lm], adc = a_dst2[lm];
#pragma unroll
    for (int r = 0; r < 4; ++r) {
        int grow = m0 + wv * 16 + lk * 4 + r;
        float v = acc[r];
        float ps = v * asc, pd = v * adc;
#pragma unroll
        for (int o = 1; o < 16; o <<= 1) {
            ps += __shfl_xor(ps, o);
            pd += __shfl_xor(pd, o);
        }
        if (grow < M) {
            h2[(size_t)grow * OUT_CH + lm] = v;
            if (lm == 0) {
                ssrc2[grow] = ps;
                sdst2[grow] = pd;
            }
        }
    }
}

// ---------------- layer-2 alpha precompute ---------------------------------
__global__ __launch_bounds__(256) void agg2a_kernel(const float* __restrict__ ssrc2,
                                                    const float* __restrict__ sdst2,
                                                    const int* __restrict__ row_start,
                                                    const int* __restrict__ srcs,
                                                    float* __restrict__ alpha2) {
    int d = blockIdx.x * 4 + (threadIdx.x >> 6);
    int l = threadIdx.x & 63;
    int start = row_start[d], end = row_start[d + 1];
    float sdst = sdst2[d];
    auto comp = [&](int i) -> float {
        int s = srcs[i];
        float e = ssrc2[s] + sdst;
        return e > 0.f ? e : NEG_SLOPE * e;
    };
    float e0 = NEGINF, e1 = NEGINF;
    int i0 = start + l;
    if (i0 < end) e0 = comp(i0);
    if (i0 + 64 < end) e1 = comp(i0 + 64);
    float mx = fmaxf(e0, e1);
    for (int i = i0 + 128; i < end; i += 64) mx = fmaxf(mx, comp(i));
#pragma unroll
    for (int o = 1; o < 64; o <<= 1) mx = fmaxf(mx, __shfl_xor(mx, o));
    float s0 = __expf(e0 - mx), s1 = __expf(e1 - mx);
    float ssum = s0 + s1;
    for (int i = i0 + 128; i < end; i += 64) ssum += __expf(comp(i) - mx);
#pragma unroll
    for (int o = 1; o < 64; o <<= 1) ssum += __shfl_xor(ssum, o);
    float inv = 1.f / (ssum + EPS_SM);
    if (i0 < end) alpha2[i0] = s0 * inv;
    if (i0 + 64 < end) alpha2[i0 + 64] = s1 * inv;
    for (int i = i0 + 128; i < end; i += 64) alpha2[i] = __expf(comp(i) - mx) * inv;
}

// ---------------- layer-2 aggregate + bias ---------------------------------
__global__ __launch_bounds__(256) void agg2b_kernel(const float* __restrict__ h2,
                                                    const float* __restrict__ alpha2,
                                                    const int* __restrict__ row_start,
                                                    const int* __restrict__ srcs,
                                                    const float* __restrict__ b2,
                                                    float* __restrict__ out) {
    int d = blockIdx.x * 4 + (threadIdx.x >> 6);
    int l = threadIdx.x & 63;
    int start = row_start[d], end = row_start[d + 1];
    int j = l >> 4, c = l & 15;
    float acc = 0.f;
    int i = start + j;
    for (; i + 4 < end; i += 8) {
        int sA = srcs[i], sB = srcs[i + 4];
        float aA = alpha2[i], aB = alpha2[i + 4];
        acc += aA * h2[(size_t)sA * OUT_CH + c] + aB * h2[(size_t)sB * OUT_CH + c];
    }
    for (; i < end; i += 4) {
        int s = srcs[i];
        acc += alpha2[i] * h2[(size_t)s * OUT_CH + c];
    }
    acc += __shfl_xor(acc, 16);
    acc += __shfl_xor(acc, 32);
    if (l < 16) out[(size_t)d * OUT_CH + c] = acc + b2[c];
}

extern "C" void kernel_launch(void* const* d_in, const int* in_sizes, int n_in,
                              void* d_out, int out_size, void* d_ws, size_t ws_size,
                              hipStream_t stream) {
    const float* x      = (const float*)d_in[0];
    const int*   ei     = (const int*)d_in[1];
    const float* W1     = (const float*)d_in[2];
    const float* a_src1 = (const float*)d_in[3];
    const float* a_dst1 = (const float*)d_in[4];
    const float* b1     = (const float*)d_in[5];
    const float* W2     = (const float*)d_in[6];
    const float* a_src2 = (const float*)d_in[7];
    const float* a_dst2 = (const float*)d_in[8];
    const float* b2     = (const float*)d_in[9];
    float* out = (float*)d_out;

    const int E = in_sizes[1] / 2;
    const int Etot = E + NN;
    const int* src_arr = ei;
    const int* dst_arr = ei + E;

    size_t off = 0;
    auto carve = [&](size_t bytes) -> void* {
        void* r = (char*)d_ws + off;
        off += (bytes + 255) & ~(size_t)255;
        return r;
    };
    unsigned short* h1b  = (unsigned short*)carve((size_t)NN * C1 * 2);
    unsigned short* out1b= (unsigned short*)carve((size_t)NN * C1 * 2);
    unsigned short* w1t  = (unsigned short*)carve((size_t)IN_CH * C1 * 2);
    unsigned short* w2b  = (unsigned short*)carve((size_t)C1 * OUT_CH * 2);
    float* ssrc1 = (float*)carve((size_t)NN * HEADS * 4);
    float* sdst1 = (float*)carve((size_t)NN * HEADS * 4);
    float* h2    = (float*)carve((size_t)NN * OUT_CH * 4);
    float* ssrc2 = (float*)carve((size_t)NN * 4);
    float* sdst2 = (float*)carve((size_t)NN * 4);
    float* alpha1= (float*)carve((size_t)Etot * HEADS * 4);
    float* alpha2= (float*)carve((size_t)Etot * 4);
    int* deg     = (int*)carve((size_t)NN * 4);
    int* rowst   = (int*)carve((size_t)(NN + 1) * 4);
    int* cursor  = (int*)carve((size_t)NN * 4);
    int* srcs    = (int*)carve((size_t)Etot * 4);
    int* bsum    = (int*)carve(64 * 4);

    const int NB = (NN + SCAN_CHUNK - 1) / SCAN_CHUNK;   // 49

    // ---- CSR build ----
    hipMemsetAsync(deg, 0, (size_t)NN * 4, stream);
    hist_kernel<<<1024, 256, 0, stream>>>(dst_arr, deg, Etot, E);
    scan_blk_kernel<<<NB, 256, 0, stream>>>(deg, rowst, bsum, NN);
    scan_bsum_kernel<<<1, 64, 0, stream>>>(bsum, NB, rowst, NN, Etot);
    scan_add_kernel<<<NB, 256, 0, stream>>>(bsum, rowst, cursor, NN);
    scatter_kernel<<<1024, 256, 0, stream>>>(src_arr, dst_arr, cursor, srcs, Etot, E);

    // ---- weights prep ----
    cvt_weights<<<144, 256, 0, stream>>>(W1, W2, w1t, w2b);

    // ---- layer 1 ----
    gemm1_mfma<<<(NN + 63) / 64, 256, 0, stream>>>(x, w1t, h1b, NN);
    scores1_kernel<<<NN / 4, 256, 0, stream>>>(h1b, a_src1, a_dst1, ssrc1, sdst1);
    agg1a_kernel<<<NN / 4, 256, 0, stream>>>(ssrc1, sdst1, rowst, srcs, alpha1);
    agg1b_kernel<<<NN / 4, 256, 0, stream>>>(h1b, alpha1, rowst, srcs, b1, out1b);

    // ---- layer 2 ----
    gemm2_mfma<<<(NN + 63) / 64, 256, 0, stream>>>(out1b, w2b, a_src2, a_dst2,
                                                   h2, ssrc2, sdst2, NN);
    agg2a_kernel<<<NN / 4, 256, 0, stream>>>(ssrc2, sdst2, rowst, srcs, alpha2);
    agg2b_kernel<<<NN / 4, 256, 0, stream>>>(h2, alpha2, rowst, srcs, b2, out);
}

// Round 5
// 196.853 us; speedup vs baseline: 2.7630x; 1.3371x over previous
//
#include <hip/hip_runtime.h>
#include <cstdint>
#include <cstddef>

#define NN 50000
#define IN_CH 128
#define C1 256        // HEADS*HID
#define HID 64
#define HEADS 4
#define OUT_CH 16
#define NEG_SLOPE 0.2f
#define EPS_SM 1e-16f
#define NEGINF -3.4e38f
#define NBUK ((NN + 255) >> 8)   // 196 buckets of 256 dst nodes

typedef __attribute__((ext_vector_type(8))) short bf16x8;
typedef __attribute__((ext_vector_type(4))) float f32x4;

__device__ __forceinline__ unsigned short f2b(float f) {
    unsigned int u = __float_as_uint(f);
    u += 0x7fffu + ((u >> 16) & 1u);   // round-to-nearest-even
    return (unsigned short)(u >> 16);
}
__device__ __forceinline__ float b2f_lo(unsigned int packed) {
    return __uint_as_float(packed << 16);
}
__device__ __forceinline__ float b2f_hi(unsigned int packed) {
    return __uint_as_float(packed & 0xffff0000u);
}

// -------- weight prep: w1t[n][k] bf16 (n-major), w2b[c][k] bf16 ------------
__global__ void cvt_weights(const float* __restrict__ W1, const float* __restrict__ W2,
                            unsigned short* __restrict__ w1t, unsigned short* __restrict__ w2b) {
    int b = blockIdx.x, t = threadIdx.x;
    if (b < 128) {
        w1t[t * 128 + b] = f2b(W1[b * 256 + t]);
    } else {
        int k = (b - 128) * 16 + (t >> 4);
        int c = t & 15;
        w2b[c * 256 + k] = f2b(W2[k * 16 + c]);
    }
}

// ---------------- GEMM1 (MFMA bf16): h1b[N,256] = x[N,128] @ W1 ------------
__global__ __launch_bounds__(256) void gemm1_mfma(const float* __restrict__ X,
                                                  const unsigned short* __restrict__ w1t,
                                                  unsigned short* __restrict__ h1b, int M) {
    __shared__ unsigned short xb[64 * 128];    // 16KB, swizzled
    __shared__ unsigned short wt[256 * 128];   // 64KB, swizzled (w1t staged)
    int tid = threadIdx.x;
    int m0 = blockIdx.x * 64;
    {
        const uint4* gp = (const uint4*)w1t;
#pragma unroll
        for (int r = 0; r < 16; ++r) {
            int idx = r * 256 + tid;
            int byte = idx * 16;
            int row = byte >> 8;
            int cb = byte & 255;
            uint4 v = gp[idx];
            *(uint4*)((char*)wt + row * 256 + (cb ^ ((row & 7) << 4))) = v;
        }
    }
    {
#pragma unroll
        for (int r = 0; r < 8; ++r) {
            int f = r * 256 + tid;   // float4 index
            int e = f * 4;
            int row = e >> 7, col = e & 127;
            float4 v = make_float4(0.f, 0.f, 0.f, 0.f);
            if (m0 + row < M) v = *(const float4*)&X[(size_t)(m0 + row) * 128 + col];
            ushort4 bb;
            bb.x = f2b(v.x); bb.y = f2b(v.y); bb.z = f2b(v.z); bb.w = f2b(v.w);
            *(ushort4*)((char*)xb + row * 256 + ((col * 2) ^ ((row & 7) << 4))) = bb;
        }
    }
    __syncthreads();
    int wv = tid >> 6, l = tid & 63;
    int lm = l & 15, lk = l >> 4;
    int swz = (lm & 7) << 4;
    f32x4 acc[4][4];
#pragma unroll
    for (int a = 0; a < 4; ++a)
#pragma unroll
        for (int b = 0; b < 4; ++b) acc[a][b] = (f32x4){0.f, 0.f, 0.f, 0.f};
#pragma unroll
    for (int kk = 0; kk < 4; ++kk) {
        int kb = (kk * 64 + lk * 16) ^ swz;
        bf16x8 af[4], bfr[4];
#pragma unroll
        for (int mf = 0; mf < 4; ++mf)
            af[mf] = *(const bf16x8*)((const char*)xb + (mf * 16 + lm) * 256 + kb);
#pragma unroll
        for (int nt = 0; nt < 4; ++nt)
            bfr[nt] = *(const bf16x8*)((const char*)wt + (wv * 64 + nt * 16 + lm) * 256 + kb);
#pragma unroll
        for (int mf = 0; mf < 4; ++mf)
#pragma unroll
            for (int nt = 0; nt < 4; ++nt)
                acc[mf][nt] = __builtin_amdgcn_mfma_f32_16x16x32_bf16(af[mf], bfr[nt], acc[mf][nt], 0, 0, 0);
    }
#pragma unroll
    for (int mf = 0; mf < 4; ++mf) {
#pragma unroll
        for (int r = 0; r < 4; ++r) {
            int row = m0 + mf * 16 + lk * 4 + r;
            if (row < M) {
#pragma unroll
                for (int nt = 0; nt < 4; ++nt)
                    h1b[(size_t)row * 256 + wv * 64 + nt * 16 + lm] = f2b(acc[mf][nt][r]);
            }
        }
    }
}

// ---------------- scores1 (16 lanes per node) ------------------------------
__global__ __launch_bounds__(256) void scores1_kernel(const unsigned short* __restrict__ h1b,
                                                      const float* __restrict__ a_src,
                                                      const float* __restrict__ a_dst,
                                                      float* __restrict__ s_src,
                                                      float* __restrict__ s_dst) {
    int n = blockIdx.x * 4 + (threadIdx.x >> 6);
    int l = threadIdx.x & 63;
    int h = l >> 4;
    uint2 hv = *(const uint2*)&h1b[(size_t)n * C1 + l * 4];
    float4 av = *(const float4*)&a_src[l * 4];
    float4 dv = *(const float4*)&a_dst[l * 4];
    float x0 = b2f_lo(hv.x), x1 = b2f_hi(hv.x), x2 = b2f_lo(hv.y), x3 = b2f_hi(hv.y);
    float ps = x0 * av.x + x1 * av.y + x2 * av.z + x3 * av.w;
    float pd = x0 * dv.x + x1 * dv.y + x2 * dv.z + x3 * dv.w;
#pragma unroll
    for (int o = 1; o < 16; o <<= 1) {
        ps += __shfl_xor(ps, o);
        pd += __shfl_xor(pd, o);
    }
    if ((l & 15) == 0) {
        s_src[n * HEADS + h] = ps;
        s_dst[n * HEADS + h] = pd;
    }
}

// ================= CSR build via dst-buckets (196 x 256 nodes) =============
// Pass 1: per-block LDS histogram of bucket counts -> global atomics
__global__ __launch_bounds__(256) void bucket_count(const int* __restrict__ dst_arr,
                                                    int* __restrict__ bcount,
                                                    int Etot, int E) {
    __shared__ int cnt[NBUK];
    int t = threadIdx.x;
    for (int i = t; i < NBUK; i += 256) cnt[i] = 0;
    __syncthreads();
    for (int i = blockIdx.x * 256 + t; i < Etot; i += gridDim.x * 256) {
        int dst = (i < E) ? dst_arr[i] : (i - E);
        atomicAdd(&cnt[dst >> 8], 1);
    }
    __syncthreads();
    for (int i = t; i < NBUK; i += 256)
        if (cnt[i]) atomicAdd(&bcount[i], cnt[i]);
}

// Pass 2: exclusive scan of 196 bucket counts (single block)
__global__ __launch_bounds__(256) void bucket_scan(const int* __restrict__ bcount,
                                                   int* __restrict__ bbase,
                                                   int* __restrict__ bcursor,
                                                   int* __restrict__ rowst, int Etot) {
    __shared__ int s[256];
    int t = threadIdx.x;
    int x = (t < NBUK) ? bcount[t] : 0;
    s[t] = x;
    __syncthreads();
    for (int off = 1; off < 256; off <<= 1) {
        int v = (t >= off) ? s[t - off] : 0;
        __syncthreads();
        s[t] += v;
        __syncthreads();
    }
    int excl = s[t] - x;
    if (t < NBUK) {
        bbase[t] = excl;
        bcursor[t] = excl;
    }
    if (t == 0) {
        bbase[NBUK] = Etot;
        rowst[NN] = Etot;
    }
}

// Pass 3: scatter edges into bucket regions, packed (dst_local<<16)|src.
// Per-block LDS count + one global reservation per bucket -> contiguous writes.
__global__ __launch_bounds__(256) void bucket_scatter(const int* __restrict__ src_arr,
                                                      const int* __restrict__ dst_arr,
                                                      int* __restrict__ bcursor,
                                                      unsigned int* __restrict__ ebuf,
                                                      int Etot, int E) {
    __shared__ int cnt[NBUK];
    __shared__ int cur[NBUK];
    int t = threadIdx.x;
    for (int i = t; i < NBUK; i += 256) cnt[i] = 0;
    __syncthreads();
    for (int i = blockIdx.x * 256 + t; i < Etot; i += gridDim.x * 256) {
        int dst = (i < E) ? dst_arr[i] : (i - E);
        atomicAdd(&cnt[dst >> 8], 1);
    }
    __syncthreads();
    for (int i = t; i < NBUK; i += 256)
        cur[i] = cnt[i] ? atomicAdd(&bcursor[i], cnt[i]) : 0;
    __syncthreads();
    for (int i = blockIdx.x * 256 + t; i < Etot; i += gridDim.x * 256) {
        int dst, src;
        if (i < E) { dst = dst_arr[i]; src = src_arr[i]; }
        else { dst = i - E; src = i - E; }
        int pos = atomicAdd(&cur[dst >> 8], 1);
        ebuf[pos] = ((unsigned int)(dst & 255) << 16) | (unsigned int)src;
    }
}

// Pass 4: one block per bucket -> local histogram + scan + scatter (all LDS-local)
__global__ __launch_bounds__(256) void bucket_csr(const unsigned int* __restrict__ ebuf,
                                                  const int* __restrict__ bbase,
                                                  int* __restrict__ rowst,
                                                  int* __restrict__ srcs) {
    __shared__ int sdeg[256];
    __shared__ int scur[256];
    int t = threadIdx.x, b = blockIdx.x;
    int ebase = bbase[b], eend = bbase[b + 1];
    sdeg[t] = 0;
    __syncthreads();
    for (int i = ebase + t; i < eend; i += 256)
        atomicAdd(&sdeg[ebuf[i] >> 16], 1);
    __syncthreads();
    int x = sdeg[t];
    __syncthreads();
    for (int off = 1; off < 256; off <<= 1) {
        int v = (t >= off) ? sdeg[t - off] : 0;
        __syncthreads();
        sdeg[t] += v;
        __syncthreads();
    }
    int excl = sdeg[t] - x;
    int gnode = b * 256 + t;
    if (gnode < NN) rowst[gnode] = ebase + excl;
    scur[t] = excl;
    __syncthreads();
    for (int i = ebase + t; i < eend; i += 256) {
        unsigned int e = ebuf[i];
        int pos = atomicAdd(&scur[e >> 16], 1);
        srcs[ebase + pos] = (int)(e & 0xffffu);
    }
}

// ---------------- layer-1 alpha precompute ---------------------------------
__global__ __launch_bounds__(256) void agg1a_kernel(const float* __restrict__ ssrc1,
                                                    const float* __restrict__ sdst1,
                                                    const int* __restrict__ row_start,
                                                    const int* __restrict__ srcs,
                                                    float* __restrict__ alpha1) {
    int d = blockIdx.x * 4 + (threadIdx.x >> 6);
    int l = threadIdx.x & 63;
    int sub = l & 15, h = l >> 4;
    int start = row_start[d], end = row_start[d + 1];
    float sdst = sdst1[d * HEADS + h];
    float e0 = NEGINF, e1 = NEGINF, e2 = NEGINF, e3 = NEGINF;
    int i0 = start + sub;
    auto comp = [&](int i) -> float {
        int s = srcs[i];
        float e = ssrc1[s * HEADS + h] + sdst;
        return e > 0.f ? e : NEG_SLOPE * e;
    };
    if (i0 < end) e0 = comp(i0);
    if (i0 + 16 < end) e1 = comp(i0 + 16);
    if (i0 + 32 < end) e2 = comp(i0 + 32);
    if (i0 + 48 < end) e3 = comp(i0 + 48);
    float mx = fmaxf(fmaxf(e0, e1), fmaxf(e2, e3));
    for (int i = i0 + 64; i < end; i += 16) mx = fmaxf(mx, comp(i));   // rare
#pragma unroll
    for (int o = 1; o < 16; o <<= 1) mx = fmaxf(mx, __shfl_xor(mx, o));
    float s0 = __expf(e0 - mx), s1 = __expf(e1 - mx);
    float s2 = __expf(e2 - mx), s3 = __expf(e3 - mx);
    float ssum = s0 + s1 + s2 + s3;
    for (int i = i0 + 64; i < end; i += 16) ssum += __expf(comp(i) - mx);
#pragma unroll
    for (int o = 1; o < 16; o <<= 1) ssum += __shfl_xor(ssum, o);
    float inv = 1.f / (ssum + EPS_SM);
    if (i0 < end) alpha1[i0 * 4 + h] = s0 * inv;
    if (i0 + 16 < end) alpha1[(i0 + 16) * 4 + h] = s1 * inv;
    if (i0 + 32 < end) alpha1[(i0 + 32) * 4 + h] = s2 * inv;
    if (i0 + 48 < end) alpha1[(i0 + 48) * 4 + h] = s3 * inv;
    for (int i = i0 + 64; i < end; i += 16) alpha1[i * 4 + h] = __expf(comp(i) - mx) * inv;
}

// ---------------- layer-1 aggregate + bias + ELU + bf16 store --------------
__global__ __launch_bounds__(256) void agg1b_kernel(const unsigned short* __restrict__ h1b,
                                                    const float* __restrict__ alpha1,
                                                    const int* __restrict__ row_start,
                                                    const int* __restrict__ srcs,
                                                    const float* __restrict__ b1,
                                                    unsigned short* __restrict__ out1b) {
    int d = blockIdx.x * 4 + (threadIdx.x >> 6);
    int l = threadIdx.x & 63;
    int h = l >> 4;
    int start = row_start[d], end = row_start[d + 1];
    float4 acc = make_float4(0.f, 0.f, 0.f, 0.f);
    int i = start;
    for (; i + 4 <= end; i += 4) {
        int sA = srcs[i], sB = srcs[i + 1], sC = srcs[i + 2], sD = srcs[i + 3];
        float aA = alpha1[i * 4 + h], aB = alpha1[(i + 1) * 4 + h];
        float aC = alpha1[(i + 2) * 4 + h], aD = alpha1[(i + 3) * 4 + h];
        uint2 vA = *(const uint2*)&h1b[(size_t)sA * C1 + l * 4];
        uint2 vB = *(const uint2*)&h1b[(size_t)sB * C1 + l * 4];
        uint2 vC = *(const uint2*)&h1b[(size_t)sC * C1 + l * 4];
        uint2 vD = *(const uint2*)&h1b[(size_t)sD * C1 + l * 4];
        acc.x += aA * b2f_lo(vA.x) + aB * b2f_lo(vB.x) + aC * b2f_lo(vC.x) + aD * b2f_lo(vD.x);
        acc.y += aA * b2f_hi(vA.x) + aB * b2f_hi(vB.x) + aC * b2f_hi(vC.x) + aD * b2f_hi(vD.x);
        acc.z += aA * b2f_lo(vA.y) + aB * b2f_lo(vB.y) + aC * b2f_lo(vC.y) + aD * b2f_lo(vD.y);
        acc.w += aA * b2f_hi(vA.y) + aB * b2f_hi(vB.y) + aC * b2f_hi(vC.y) + aD * b2f_hi(vD.y);
    }
    for (; i < end; ++i) {
        int s = srcs[i];
        float a = alpha1[i * 4 + h];
        uint2 v = *(const uint2*)&h1b[(size_t)s * C1 + l * 4];
        acc.x += a * b2f_lo(v.x);
        acc.y += a * b2f_hi(v.x);
        acc.z += a * b2f_lo(v.y);
        acc.w += a * b2f_hi(v.y);
    }
    int cb = l * 4;
    float4 bb = *(const float4*)&b1[cb];
    float v0 = acc.x + bb.x, v1 = acc.y + bb.y, v2 = acc.z + bb.z, v3 = acc.w + bb.w;
    v0 = v0 > 0.f ? v0 : (__expf(v0) - 1.f);
    v1 = v1 > 0.f ? v1 : (__expf(v1) - 1.f);
    v2 = v2 > 0.f ? v2 : (__expf(v2) - 1.f);
    v3 = v3 > 0.f ? v3 : (__expf(v3) - 1.f);
    ushort4 o;
    o.x = f2b(v0); o.y = f2b(v1); o.z = f2b(v2); o.w = f2b(v3);
    *(ushort4*)&out1b[(size_t)d * C1 + cb] = o;
}

// ------- GEMM2 (MFMA): h2[N,16] = out1b[N,256] @ W2b  + fused scores -------
__global__ __launch_bounds__(256) void gemm2_mfma(const unsigned short* __restrict__ out1b,
                                                  const unsigned short* __restrict__ w2b,
                                                  const float* __restrict__ a_src2,
                                                  const float* __restrict__ a_dst2,
                                                  float* __restrict__ h2,
                                                  float* __restrict__ ssrc2,
                                                  float* __restrict__ sdst2, int M) {
    __shared__ char ab[64 * 528];
    int tid = threadIdx.x;
    int m0 = blockIdx.x * 64;
#pragma unroll
    for (int r = 0; r < 8; ++r) {
        int byte = r * 4096 + tid * 16;
        int row = byte >> 9, col = byte & 511;
        uint4 v = make_uint4(0u, 0u, 0u, 0u);
        if (m0 + row < M)
            v = *(const uint4*)((const char*)out1b + (size_t)(m0 + row) * 512 + col);
        *(uint4*)(ab + row * 528 + col) = v;
    }
    int wv = tid >> 6, l = tid & 63;
    int lm = l & 15, lk = l >> 4;
    bf16x8 bfr[8];
#pragma unroll
    for (int kk = 0; kk < 8; ++kk)
        bfr[kk] = *(const bf16x8*)&w2b[lm * 256 + lk * 8 + kk * 32];
    __syncthreads();
    f32x4 acc = (f32x4){0.f, 0.f, 0.f, 0.f};
    const char* base = ab + (wv * 16 + lm) * 528 + lk * 16;
#pragma unroll
    for (int kk = 0; kk < 8; ++kk) {
        bf16x8 af = *(const bf16x8*)(base + kk * 64);
        acc = __builtin_amdgcn_mfma_f32_16x16x32_bf16(af, bfr[kk], acc, 0, 0, 0);
    }
    float asc = a_src2[lm], adc = a_dst2[lm];
#pragma unroll
    for (int r = 0; r < 4; ++r) {
        int grow = m0 + wv * 16 + lk * 4 + r;
        float v = acc[r];
        float ps = v * asc, pd = v * adc;
#pragma unroll
        for (int o = 1; o < 16; o <<= 1) {
            ps += __shfl_xor(ps, o);
            pd += __shfl_xor(pd, o);
        }
        if (grow < M) {
            h2[(size_t)grow * OUT_CH + lm] = v;
            if (lm == 0) {
                ssrc2[grow] = ps;
                sdst2[grow] = pd;
            }
        }
    }
}

// ---------------- layer-2 alpha precompute ---------------------------------
__global__ __launch_bounds__(256) void agg2a_kernel(const float* __restrict__ ssrc2,
                                                    const float* __restrict__ sdst2,
                                                    const int* __restrict__ row_start,
                                                    const int* __restrict__ srcs,
                                                    float* __restrict__ alpha2) {
    int d = blockIdx.x * 4 + (threadIdx.x >> 6);
    int l = threadIdx.x & 63;
    int start = row_start[d], end = row_start[d + 1];
    float sdst = sdst2[d];
    auto comp = [&](int i) -> float {
        int s = srcs[i];
        float e = ssrc2[s] + sdst;
        return e > 0.f ? e : NEG_SLOPE * e;
    };
    float e0 = NEGINF, e1 = NEGINF;
    int i0 = start + l;
    if (i0 < end) e0 = comp(i0);
    if (i0 + 64 < end) e1 = comp(i0 + 64);
    float mx = fmaxf(e0, e1);
    for (int i = i0 + 128; i < end; i += 64) mx = fmaxf(mx, comp(i));
#pragma unroll
    for (int o = 1; o < 64; o <<= 1) mx = fmaxf(mx, __shfl_xor(mx, o));
    float s0 = __expf(e0 - mx), s1 = __expf(e1 - mx);
    float ssum = s0 + s1;
    for (int i = i0 + 128; i < end; i += 64) ssum += __expf(comp(i) - mx);
#pragma unroll
    for (int o = 1; o < 64; o <<= 1) ssum += __shfl_xor(ssum, o);
    float inv = 1.f / (ssum + EPS_SM);
    if (i0 < end) alpha2[i0] = s0 * inv;
    if (i0 + 64 < end) alpha2[i0 + 64] = s1 * inv;
    for (int i = i0 + 128; i < end; i += 64) alpha2[i] = __expf(comp(i) - mx) * inv;
}

// ---------------- layer-2 aggregate + bias ---------------------------------
__global__ __launch_bounds__(256) void agg2b_kernel(const float* __restrict__ h2,
                                                    const float* __restrict__ alpha2,
                                                    const int* __restrict__ row_start,
                                                    const int* __restrict__ srcs,
                                                    const float* __restrict__ b2,
                                                    float* __restrict__ out) {
    int d = blockIdx.x * 4 + (threadIdx.x >> 6);
    int l = threadIdx.x & 63;
    int start = row_start[d], end = row_start[d + 1];
    int j = l >> 4, c = l & 15;
    float acc = 0.f;
    int i = start + j;
    for (; i + 4 < end; i += 8) {
        int sA = srcs[i], sB = srcs[i + 4];
        float aA = alpha2[i], aB = alpha2[i + 4];
        acc += aA * h2[(size_t)sA * OUT_CH + c] + aB * h2[(size_t)sB * OUT_CH + c];
    }
    for (; i < end; i += 4) {
        int s = srcs[i];
        acc += alpha2[i] * h2[(size_t)s * OUT_CH + c];
    }
    acc += __shfl_xor(acc, 16);
    acc += __shfl_xor(acc, 32);
    if (l < 16) out[(size_t)d * OUT_CH + c] = acc + b2[c];
}

extern "C" void kernel_launch(void* const* d_in, const int* in_sizes, int n_in,
                              void* d_out, int out_size, void* d_ws, size_t ws_size,
                              hipStream_t stream) {
    const float* x      = (const float*)d_in[0];
    const int*   ei     = (const int*)d_in[1];
    const float* W1     = (const float*)d_in[2];
    const float* a_src1 = (const float*)d_in[3];
    const float* a_dst1 = (const float*)d_in[4];
    const float* b1     = (const float*)d_in[5];
    const float* W2     = (const float*)d_in[6];
    const float* a_src2 = (const float*)d_in[7];
    const float* a_dst2 = (const float*)d_in[8];
    const float* b2     = (const float*)d_in[9];
    float* out = (float*)d_out;

    const int E = in_sizes[1] / 2;
    const int Etot = E + NN;
    const int* src_arr = ei;
    const int* dst_arr = ei + E;

    size_t off = 0;
    auto carve = [&](size_t bytes) -> void* {
        void* r = (char*)d_ws + off;
        off += (bytes + 255) & ~(size_t)255;
        return r;
    };
    unsigned short* h1b  = (unsigned short*)carve((size_t)NN * C1 * 2);
    unsigned short* out1b= (unsigned short*)carve((size_t)NN * C1 * 2);
    unsigned short* w1t  = (unsigned short*)carve((size_t)IN_CH * C1 * 2);
    unsigned short* w2b  = (unsigned short*)carve((size_t)C1 * OUT_CH * 2);
    float* ssrc1 = (float*)carve((size_t)NN * HEADS * 4);
    float* sdst1 = (float*)carve((size_t)NN * HEADS * 4);
    float* h2    = (float*)carve((size_t)NN * OUT_CH * 4);
    float* ssrc2 = (float*)carve((size_t)NN * 4);
    float* sdst2 = (float*)carve((size_t)NN * 4);
    float* alpha1= (float*)carve((size_t)Etot * HEADS * 4);
    float* alpha2= (float*)carve((size_t)Etot * 4);
    int* rowst   = (int*)carve((size_t)(NN + 1) * 4);
    int* srcs    = (int*)carve((size_t)Etot * 4);
    unsigned int* ebuf = (unsigned int*)carve((size_t)Etot * 4);
    int* bcount  = (int*)carve((size_t)NBUK * 4);
    int* bbase   = (int*)carve((size_t)(NBUK + 1) * 4);
    int* bcursor = (int*)carve((size_t)NBUK * 4);

    // ---- CSR build via buckets ----
    hipMemsetAsync(bcount, 0, (size_t)NBUK * 4, stream);
    bucket_count<<<256, 256, 0, stream>>>(dst_arr, bcount, Etot, E);
    bucket_scan<<<1, 256, 0, stream>>>(bcount, bbase, bcursor, rowst, Etot);
    bucket_scatter<<<256, 256, 0, stream>>>(src_arr, dst_arr, bcursor, ebuf, Etot, E);
    bucket_csr<<<NBUK, 256, 0, stream>>>(ebuf, bbase, rowst, srcs);

    // ---- weights prep ----
    cvt_weights<<<144, 256, 0, stream>>>(W1, W2, w1t, w2b);

    // ---- layer 1 ----
    gemm1_mfma<<<(NN + 63) / 64, 256, 0, stream>>>(x, w1t, h1b, NN);
    scores1_kernel<<<NN / 4, 256, 0, stream>>>(h1b, a_src1, a_dst1, ssrc1, sdst1);
    agg1a_kernel<<<NN / 4, 256, 0, stream>>>(ssrc1, sdst1, rowst, srcs, alpha1);
    agg1b_kernel<<<NN / 4, 256, 0, stream>>>(h1b, alpha1, rowst, srcs, b1, out1b);

    // ---- layer 2 ----
    gemm2_mfma<<<(NN + 63) / 64, 256, 0, stream>>>(out1b, w2b, a_src2, a_dst2,
                                                   h2, ssrc2, sdst2, NN);
    agg2a_kernel<<<NN / 4, 256, 0, stream>>>(ssrc2, sdst2, rowst, srcs, alpha2);
    agg2b_kernel<<<NN / 4, 256, 0, stream>>>(h2, alpha2, rowst, srcs, b2, out);
}

// Round 6
// 190.608 us; speedup vs baseline: 2.8535x; 1.0328x over previous
//
#include <hip/hip_runtime.h>
#include <cstdint>
#include <cstddef>

#define NN 50000
#define IN_CH 128
#define C1 256        // HEADS*HID
#define HID 64
#define HEADS 4
#define OUT_CH 16
#define NEG_SLOPE 0.2f
#define EPS_SM 1e-16f
#define NEGINF -3.4e38f
#define NBUK ((NN + 255) >> 8)   // 196 buckets of 256 dst nodes

typedef __attribute__((ext_vector_type(8))) short bf16x8;
typedef __attribute__((ext_vector_type(4))) float f32x4;

__device__ __forceinline__ unsigned short f2b(float f) {
    unsigned int u = __float_as_uint(f);
    u += 0x7fffu + ((u >> 16) & 1u);   // round-to-nearest-even
    return (unsigned short)(u >> 16);
}
__device__ __forceinline__ float b2f_lo(unsigned int packed) {
    return __uint_as_float(packed << 16);
}
__device__ __forceinline__ float b2f_hi(unsigned int packed) {
    return __uint_as_float(packed & 0xffff0000u);
}

// -------- weight prep: w1t[n][k] bf16 (n-major), w2b[c][k] bf16 ------------
__global__ void cvt_weights(const float* __restrict__ W1, const float* __restrict__ W2,
                            unsigned short* __restrict__ w1t, unsigned short* __restrict__ w2b) {
    int b = blockIdx.x, t = threadIdx.x;
    if (b < 128) {
        w1t[t * 128 + b] = f2b(W1[b * 256 + t]);
    } else {
        int k = (b - 128) * 16 + (t >> 4);
        int c = t & 15;
        w2b[c * 256 + k] = f2b(W2[k * 16 + c]);
    }
}

// ---------------- GEMM1 (MFMA bf16): h1b[N,256] = x[N,128] @ W1 ------------
__global__ __launch_bounds__(256) void gemm1_mfma(const float* __restrict__ X,
                                                  const unsigned short* __restrict__ w1t,
                                                  unsigned short* __restrict__ h1b, int M) {
    __shared__ unsigned short xb[64 * 128];    // 16KB, swizzled
    __shared__ unsigned short wt[256 * 128];   // 64KB, swizzled (w1t staged)
    int tid = threadIdx.x;
    int m0 = blockIdx.x * 64;
    {
        const uint4* gp = (const uint4*)w1t;
#pragma unroll
        for (int r = 0; r < 16; ++r) {
            int idx = r * 256 + tid;
            int byte = idx * 16;
            int row = byte >> 8;
            int cb = byte & 255;
            uint4 v = gp[idx];
            *(uint4*)((char*)wt + row * 256 + (cb ^ ((row & 7) << 4))) = v;
        }
    }
    {
#pragma unroll
        for (int r = 0; r < 8; ++r) {
            int f = r * 256 + tid;   // float4 index
            int e = f * 4;
            int row = e >> 7, col = e & 127;
            float4 v = make_float4(0.f, 0.f, 0.f, 0.f);
            if (m0 + row < M) v = *(const float4*)&X[(size_t)(m0 + row) * 128 + col];
            ushort4 bb;
            bb.x = f2b(v.x); bb.y = f2b(v.y); bb.z = f2b(v.z); bb.w = f2b(v.w);
            *(ushort4*)((char*)xb + row * 256 + ((col * 2) ^ ((row & 7) << 4))) = bb;
        }
    }
    __syncthreads();
    int wv = tid >> 6, l = tid & 63;
    int lm = l & 15, lk = l >> 4;
    int swz = (lm & 7) << 4;
    f32x4 acc[4][4];
#pragma unroll
    for (int a = 0; a < 4; ++a)
#pragma unroll
        for (int b = 0; b < 4; ++b) acc[a][b] = (f32x4){0.f, 0.f, 0.f, 0.f};
#pragma unroll
    for (int kk = 0; kk < 4; ++kk) {
        int kb = (kk * 64 + lk * 16) ^ swz;
        bf16x8 af[4], bfr[4];
#pragma unroll
        for (int mf = 0; mf < 4; ++mf)
            af[mf] = *(const bf16x8*)((const char*)xb + (mf * 16 + lm) * 256 + kb);
#pragma unroll
        for (int nt = 0; nt < 4; ++nt)
            bfr[nt] = *(const bf16x8*)((const char*)wt + (wv * 64 + nt * 16 + lm) * 256 + kb);
#pragma unroll
        for (int mf = 0; mf < 4; ++mf)
#pragma unroll
            for (int nt = 0; nt < 4; ++nt)
                acc[mf][nt] = __builtin_amdgcn_mfma_f32_16x16x32_bf16(af[mf], bfr[nt], acc[mf][nt], 0, 0, 0);
    }
#pragma unroll
    for (int mf = 0; mf < 4; ++mf) {
#pragma unroll
        for (int r = 0; r < 4; ++r) {
            int row = m0 + mf * 16 + lk * 4 + r;
            if (row < M) {
#pragma unroll
                for (int nt = 0; nt < 4; ++nt)
                    h1b[(size_t)row * 256 + wv * 64 + nt * 16 + lm] = f2b(acc[mf][nt][r]);
            }
        }
    }
}

// ---------------- scores1 (16 lanes per node) ------------------------------
__global__ __launch_bounds__(256) void scores1_kernel(const unsigned short* __restrict__ h1b,
                                                      const float* __restrict__ a_src,
                                                      const float* __restrict__ a_dst,
                                                      float* __restrict__ s_src,
                                                      float* __restrict__ s_dst) {
    int n = blockIdx.x * 4 + (threadIdx.x >> 6);
    int l = threadIdx.x & 63;
    int h = l >> 4;
    uint2 hv = *(const uint2*)&h1b[(size_t)n * C1 + l * 4];
    float4 av = *(const float4*)&a_src[l * 4];
    float4 dv = *(const float4*)&a_dst[l * 4];
    float x0 = b2f_lo(hv.x), x1 = b2f_hi(hv.x), x2 = b2f_lo(hv.y), x3 = b2f_hi(hv.y);
    float ps = x0 * av.x + x1 * av.y + x2 * av.z + x3 * av.w;
    float pd = x0 * dv.x + x1 * dv.y + x2 * dv.z + x3 * dv.w;
#pragma unroll
    for (int o = 1; o < 16; o <<= 1) {
        ps += __shfl_xor(ps, o);
        pd += __shfl_xor(pd, o);
    }
    if ((l & 15) == 0) {
        s_src[n * HEADS + h] = ps;
        s_dst[n * HEADS + h] = pd;
    }
}

// ================= CSR build via dst-buckets (196 x 256 nodes) =============
__global__ __launch_bounds__(256) void bucket_count(const int* __restrict__ dst_arr,
                                                    int* __restrict__ bcount,
                                                    int Etot, int E) {
    __shared__ int cnt[NBUK];
    int t = threadIdx.x;
    for (int i = t; i < NBUK; i += 256) cnt[i] = 0;
    __syncthreads();
    for (int i = blockIdx.x * 256 + t; i < Etot; i += gridDim.x * 256) {
        int dst = (i < E) ? dst_arr[i] : (i - E);
        atomicAdd(&cnt[dst >> 8], 1);
    }
    __syncthreads();
    for (int i = t; i < NBUK; i += 256)
        if (cnt[i]) atomicAdd(&bcount[i], cnt[i]);
}

__global__ __launch_bounds__(256) void bucket_scan(const int* __restrict__ bcount,
                                                   int* __restrict__ bbase,
                                                   int* __restrict__ bcursor,
                                                   int* __restrict__ rowst, int Etot) {
    __shared__ int s[256];
    int t = threadIdx.x;
    int x = (t < NBUK) ? bcount[t] : 0;
    s[t] = x;
    __syncthreads();
    for (int off = 1; off < 256; off <<= 1) {
        int v = (t >= off) ? s[t - off] : 0;
        __syncthreads();
        s[t] += v;
        __syncthreads();
    }
    int excl = s[t] - x;
    if (t < NBUK) {
        bbase[t] = excl;
        bcursor[t] = excl;
    }
    if (t == 0) {
        bbase[NBUK] = Etot;
        rowst[NN] = Etot;
    }
}

__global__ __launch_bounds__(256) void bucket_scatter(const int* __restrict__ src_arr,
                                                      const int* __restrict__ dst_arr,
                                                      int* __restrict__ bcursor,
                                                      unsigned int* __restrict__ ebuf,
                                                      int Etot, int E) {
    __shared__ int cnt[NBUK];
    __shared__ int cur[NBUK];
    int t = threadIdx.x;
    for (int i = t; i < NBUK; i += 256) cnt[i] = 0;
    __syncthreads();
    for (int i = blockIdx.x * 256 + t; i < Etot; i += gridDim.x * 256) {
        int dst = (i < E) ? dst_arr[i] : (i - E);
        atomicAdd(&cnt[dst >> 8], 1);
    }
    __syncthreads();
    for (int i = t; i < NBUK; i += 256)
        cur[i] = cnt[i] ? atomicAdd(&bcursor[i], cnt[i]) : 0;
    __syncthreads();
    for (int i = blockIdx.x * 256 + t; i < Etot; i += gridDim.x * 256) {
        int dst, src;
        if (i < E) { dst = dst_arr[i]; src = src_arr[i]; }
        else { dst = i - E; src = i - E; }
        int pos = atomicAdd(&cur[dst >> 8], 1);
        ebuf[pos] = ((unsigned int)(dst & 255) << 16) | (unsigned int)src;
    }
}

__global__ __launch_bounds__(256) void bucket_csr(const unsigned int* __restrict__ ebuf,
                                                  const int* __restrict__ bbase,
                                                  int* __restrict__ rowst,
                                                  int* __restrict__ srcs) {
    __shared__ int sdeg[256];
    __shared__ int scur[256];
    int t = threadIdx.x, b = blockIdx.x;
    int ebase = bbase[b], eend = bbase[b + 1];
    sdeg[t] = 0;
    __syncthreads();
    for (int i = ebase + t; i < eend; i += 256)
        atomicAdd(&sdeg[ebuf[i] >> 16], 1);
    __syncthreads();
    int x = sdeg[t];
    __syncthreads();
    for (int off = 1; off < 256; off <<= 1) {
        int v = (t >= off) ? sdeg[t - off] : 0;
        __syncthreads();
        sdeg[t] += v;
        __syncthreads();
    }
    int excl = sdeg[t] - x;
    int gnode = b * 256 + t;
    if (gnode < NN) rowst[gnode] = ebase + excl;
    scur[t] = excl;
    __syncthreads();
    for (int i = ebase + t; i < eend; i += 256) {
        unsigned int e = ebuf[i];
        int pos = atomicAdd(&scur[e >> 16], 1);
        srcs[ebase + pos] = (int)(e & 0xffffu);
    }
}

// ---------------- layer-1 alpha precompute ---------------------------------
__global__ __launch_bounds__(256) void agg1a_kernel(const float* __restrict__ ssrc1,
                                                    const float* __restrict__ sdst1,
                                                    const int* __restrict__ row_start,
                                                    const int* __restrict__ srcs,
                                                    float* __restrict__ alpha1) {
    int d = blockIdx.x * 4 + (threadIdx.x >> 6);
    int l = threadIdx.x & 63;
    int sub = l & 15, h = l >> 4;
    int start = row_start[d], end = row_start[d + 1];
    float sdst = sdst1[d * HEADS + h];
    float e0 = NEGINF, e1 = NEGINF, e2 = NEGINF, e3 = NEGINF;
    int i0 = start + sub;
    auto comp = [&](int i) -> float {
        int s = srcs[i];
        float e = ssrc1[s * HEADS + h] + sdst;
        return e > 0.f ? e : NEG_SLOPE * e;
    };
    if (i0 < end) e0 = comp(i0);
    if (i0 + 16 < end) e1 = comp(i0 + 16);
    if (i0 + 32 < end) e2 = comp(i0 + 32);
    if (i0 + 48 < end) e3 = comp(i0 + 48);
    float mx = fmaxf(fmaxf(e0, e1), fmaxf(e2, e3));
    for (int i = i0 + 64; i < end; i += 16) mx = fmaxf(mx, comp(i));   // rare
#pragma unroll
    for (int o = 1; o < 16; o <<= 1) mx = fmaxf(mx, __shfl_xor(mx, o));
    float s0 = __expf(e0 - mx), s1 = __expf(e1 - mx);
    float s2 = __expf(e2 - mx), s3 = __expf(e3 - mx);
    float ssum = s0 + s1 + s2 + s3;
    for (int i = i0 + 64; i < end; i += 16) ssum += __expf(comp(i) - mx);
#pragma unroll
    for (int o = 1; o < 16; o <<= 1) ssum += __shfl_xor(ssum, o);
    float inv = 1.f / (ssum + EPS_SM);
    if (i0 < end) alpha1[i0 * 4 + h] = s0 * inv;
    if (i0 + 16 < end) alpha1[(i0 + 16) * 4 + h] = s1 * inv;
    if (i0 + 32 < end) alpha1[(i0 + 32) * 4 + h] = s2 * inv;
    if (i0 + 48 < end) alpha1[(i0 + 48) * 4 + h] = s3 * inv;
    for (int i = i0 + 64; i < end; i += 16) alpha1[i * 4 + h] = __expf(comp(i) - mx) * inv;
}

// ------- layer-1 aggregate: 2 edge-slots x 32 channel-lanes, uint4 gathers --
__global__ __launch_bounds__(256) void agg1b_kernel(const unsigned short* __restrict__ h1b,
                                                    const float* __restrict__ alpha1,
                                                    const int* __restrict__ row_start,
                                                    const int* __restrict__ srcs,
                                                    const float* __restrict__ b1,
                                                    unsigned short* __restrict__ out1b) {
    int d = blockIdx.x * 4 + (threadIdx.x >> 6);
    int l = threadIdx.x & 63;
    int half = l >> 5;          // edge slot 0/1
    int cl = l & 31;            // channel lane: 8 ch = 16 B
    int h = cl >> 3;            // head
    int start = row_start[d], end = row_start[d + 1];
    float acc[8] = {};
    const int cb = cl * 8;      // channel base
    int i = start + half;
    // 4-deep unroll: this half processes edges i, i+2, i+4, i+6 (8 rows/wave in flight)
    for (; i + 6 < end; i += 8) {
        int s0 = srcs[i], s1 = srcs[i + 2], s2 = srcs[i + 4], s3 = srcs[i + 6];
        float a0 = alpha1[i * 4 + h],       a1 = alpha1[(i + 2) * 4 + h];
        float a2 = alpha1[(i + 4) * 4 + h], a3 = alpha1[(i + 6) * 4 + h];
        uint4 v0 = *(const uint4*)&h1b[(size_t)s0 * C1 + cb];
        uint4 v1 = *(const uint4*)&h1b[(size_t)s1 * C1 + cb];
        uint4 v2 = *(const uint4*)&h1b[(size_t)s2 * C1 + cb];
        uint4 v3 = *(const uint4*)&h1b[(size_t)s3 * C1 + cb];
        acc[0] += a0 * b2f_lo(v0.x) + a1 * b2f_lo(v1.x) + a2 * b2f_lo(v2.x) + a3 * b2f_lo(v3.x);
        acc[1] += a0 * b2f_hi(v0.x) + a1 * b2f_hi(v1.x) + a2 * b2f_hi(v2.x) + a3 * b2f_hi(v3.x);
        acc[2] += a0 * b2f_lo(v0.y) + a1 * b2f_lo(v1.y) + a2 * b2f_lo(v2.y) + a3 * b2f_lo(v3.y);
        acc[3] += a0 * b2f_hi(v0.y) + a1 * b2f_hi(v1.y) + a2 * b2f_hi(v2.y) + a3 * b2f_hi(v3.y);
        acc[4] += a0 * b2f_lo(v0.z) + a1 * b2f_lo(v1.z) + a2 * b2f_lo(v2.z) + a3 * b2f_lo(v3.z);
        acc[5] += a0 * b2f_hi(v0.z) + a1 * b2f_hi(v1.z) + a2 * b2f_hi(v2.z) + a3 * b2f_hi(v3.z);
        acc[6] += a0 * b2f_lo(v0.w) + a1 * b2f_lo(v1.w) + a2 * b2f_lo(v2.w) + a3 * b2f_lo(v3.w);
        acc[7] += a0 * b2f_hi(v0.w) + a1 * b2f_hi(v1.w) + a2 * b2f_hi(v2.w) + a3 * b2f_hi(v3.w);
    }
    for (; i < end; i += 2) {
        int s = srcs[i];
        float a = alpha1[i * 4 + h];
        uint4 v = *(const uint4*)&h1b[(size_t)s * C1 + cb];
        acc[0] += a * b2f_lo(v.x); acc[1] += a * b2f_hi(v.x);
        acc[2] += a * b2f_lo(v.y); acc[3] += a * b2f_hi(v.y);
        acc[4] += a * b2f_lo(v.z); acc[5] += a * b2f_hi(v.z);
        acc[6] += a * b2f_lo(v.w); acc[7] += a * b2f_hi(v.w);
    }
#pragma unroll
    for (int j = 0; j < 8; ++j) acc[j] += __shfl_xor(acc[j], 32);
    if (half == 0) {
        float4 ba = *(const float4*)&b1[cb];
        float4 bbv = *(const float4*)&b1[cb + 4];
        float v[8];
        v[0] = acc[0] + ba.x;  v[1] = acc[1] + ba.y;
        v[2] = acc[2] + ba.z;  v[3] = acc[3] + ba.w;
        v[4] = acc[4] + bbv.x; v[5] = acc[5] + bbv.y;
        v[6] = acc[6] + bbv.z; v[7] = acc[7] + bbv.w;
        bf16x8 o;
#pragma unroll
        for (int j = 0; j < 8; ++j) {
            float t = v[j] > 0.f ? v[j] : (__expf(v[j]) - 1.f);
            o[j] = (short)f2b(t);
        }
        *(bf16x8*)&out1b[(size_t)d * C1 + cb] = o;
    }
}

// ------- GEMM2 (MFMA): h2[N,16] = out1b[N,256] @ W2b  + fused scores -------
__global__ __launch_bounds__(256) void gemm2_mfma(const unsigned short* __restrict__ out1b,
                                                  const unsigned short* __restrict__ w2b,
                                                  const float* __restrict__ a_src2,
                                                  const float* __restrict__ a_dst2,
                                                  float* __restrict__ h2,
                                                  float* __restrict__ ssrc2,
                                                  float* __restrict__ sdst2, int M) {
    __shared__ char ab[64 * 528];
    int tid = threadIdx.x;
    int m0 = blockIdx.x * 64;
#pragma unroll
    for (int r = 0; r < 8; ++r) {
        int byte = r * 4096 + tid * 16;
        int row = byte >> 9, col = byte & 511;
        uint4 v = make_uint4(0u, 0u, 0u, 0u);
        if (m0 + row < M)
            v = *(const uint4*)((const char*)out1b + (size_t)(m0 + row) * 512 + col);
        *(uint4*)(ab + row * 528 + col) = v;
    }
    int wv = tid >> 6, l = tid & 63;
    int lm = l & 15, lk = l >> 4;
    bf16x8 bfr[8];
#pragma unroll
    for (int kk = 0; kk < 8; ++kk)
        bfr[kk] = *(const bf16x8*)&w2b[lm * 256 + lk * 8 + kk * 32];
    __syncthreads();
    f32x4 acc = (f32x4){0.f, 0.f, 0.f, 0.f};
    const char* base = ab + (wv * 16 + lm) * 528 + lk * 16;
#pragma unroll
    for (int kk = 0; kk < 8; ++kk) {
        bf16x8 af = *(const bf16x8*)(base + kk * 64);
        acc = __builtin_amdgcn_mfma_f32_16x16x32_bf16(af, bfr[kk], acc, 0, 0, 0);
    }
    float asc = a_src2[lm], adc = a_dst2[lm];
#pragma unroll
    for (int r = 0; r < 4; ++r) {
        int grow = m0 + wv * 16 + lk * 4 + r;
        float v = acc[r];
        float ps = v * asc, pd = v * adc;
#pragma unroll
        for (int o = 1; o < 16; o <<= 1) {
            ps += __shfl_xor(ps, o);
            pd += __shfl_xor(pd, o);
        }
        if (grow < M) {
            h2[(size_t)grow * OUT_CH + lm] = v;
            if (lm == 0) {
                ssrc2[grow] = ps;
                sdst2[grow] = pd;
            }
        }
    }
}

// ---------------- layer-2 alpha precompute ---------------------------------
__global__ __launch_bounds__(256) void agg2a_kernel(const float* __restrict__ ssrc2,
                                                    const float* __restrict__ sdst2,
                                                    const int* __restrict__ row_start,
                                                    const int* __restrict__ srcs,
                                                    float* __restrict__ alpha2) {
    int d = blockIdx.x * 4 + (threadIdx.x >> 6);
    int l = threadIdx.x & 63;
    int start = row_start[d], end = row_start[d + 1];
    float sdst = sdst2[d];
    auto comp = [&](int i) -> float {
        int s = srcs[i];
        float e = ssrc2[s] + sdst;
        return e > 0.f ? e : NEG_SLOPE * e;
    };
    float e0 = NEGINF, e1 = NEGINF;
    int i0 = start + l;
    if (i0 < end) e0 = comp(i0);
    if (i0 + 64 < end) e1 = comp(i0 + 64);
    float mx = fmaxf(e0, e1);
    for (int i = i0 + 128; i < end; i += 64) mx = fmaxf(mx, comp(i));
#pragma unroll
    for (int o = 1; o < 64; o <<= 1) mx = fmaxf(mx, __shfl_xor(mx, o));
    float s0 = __expf(e0 - mx), s1 = __expf(e1 - mx);
    float ssum = s0 + s1;
    for (int i = i0 + 128; i < end; i += 64) ssum += __expf(comp(i) - mx);
#pragma unroll
    for (int o = 1; o < 64; o <<= 1) ssum += __shfl_xor(ssum, o);
    float inv = 1.f / (ssum + EPS_SM);
    if (i0 < end) alpha2[i0] = s0 * inv;
    if (i0 + 64 < end) alpha2[i0 + 64] = s1 * inv;
    for (int i = i0 + 128; i < end; i += 64) alpha2[i] = __expf(comp(i) - mx) * inv;
}

// ------- layer-2 aggregate: 16 edge-slots x 4 lanes, float4 gathers --------
__global__ __launch_bounds__(256) void agg2b_kernel(const float* __restrict__ h2,
                                                    const float* __restrict__ alpha2,
                                                    const int* __restrict__ row_start,
                                                    const int* __restrict__ srcs,
                                                    const float* __restrict__ b2,
                                                    float* __restrict__ out) {
    int d = blockIdx.x * 4 + (threadIdx.x >> 6);
    int l = threadIdx.x & 63;
    int start = row_start[d], end = row_start[d + 1];
    int slot = l >> 2;          // 16 edge slots
    int c4 = (l & 3) * 4;       // channel base (float4)
    float4 acc = make_float4(0.f, 0.f, 0.f, 0.f);
    for (int i = start + slot; i < end; i += 16) {
        int s = srcs[i];
        float a = alpha2[i];
        float4 v = *(const float4*)&h2[(size_t)s * OUT_CH + c4];
        acc.x += a * v.x; acc.y += a * v.y; acc.z += a * v.z; acc.w += a * v.w;
    }
#pragma unroll
    for (int o = 4; o < 64; o <<= 1) {
        acc.x += __shfl_xor(acc.x, o);
        acc.y += __shfl_xor(acc.y, o);
        acc.z += __shfl_xor(acc.z, o);
        acc.w += __shfl_xor(acc.w, o);
    }
    if (l < 4) {
        float4 bb = *(const float4*)&b2[c4];
        float4 r = make_float4(acc.x + bb.x, acc.y + bb.y, acc.z + bb.z, acc.w + bb.w);
        *(float4*)&out[(size_t)d * OUT_CH + c4] = r;
    }
}

extern "C" void kernel_launch(void* const* d_in, const int* in_sizes, int n_in,
                              void* d_out, int out_size, void* d_ws, size_t ws_size,
                              hipStream_t stream) {
    const float* x      = (const float*)d_in[0];
    const int*   ei     = (const int*)d_in[1];
    const float* W1     = (const float*)d_in[2];
    const float* a_src1 = (const float*)d_in[3];
    const float* a_dst1 = (const float*)d_in[4];
    const float* b1     = (const float*)d_in[5];
    const float* W2     = (const float*)d_in[6];
    const float* a_src2 = (const float*)d_in[7];
    const float* a_dst2 = (const float*)d_in[8];
    const float* b2     = (const float*)d_in[9];
    float* out = (float*)d_out;

    const int E = in_sizes[1] / 2;
    const int Etot = E + NN;
    const int* src_arr = ei;
    const int* dst_arr = ei + E;

    size_t off = 0;
    auto carve = [&](size_t bytes) -> void* {
        void* r = (char*)d_ws + off;
        off += (bytes + 255) & ~(size_t)255;
        return r;
    };
    unsigned short* h1b  = (unsigned short*)carve((size_t)NN * C1 * 2);
    unsigned short* out1b= (unsigned short*)carve((size_t)NN * C1 * 2);
    unsigned short* w1t  = (unsigned short*)carve((size_t)IN_CH * C1 * 2);
    unsigned short* w2b  = (unsigned short*)carve((size_t)C1 * OUT_CH * 2);
    float* ssrc1 = (float*)carve((size_t)NN * HEADS * 4);
    float* sdst1 = (float*)carve((size_t)NN * HEADS * 4);
    float* h2    = (float*)carve((size_t)NN * OUT_CH * 4);
    float* ssrc2 = (float*)carve((size_t)NN * 4);
    float* sdst2 = (float*)carve((size_t)NN * 4);
    float* alpha1= (float*)carve((size_t)Etot * HEADS * 4);
    float* alpha2= (float*)carve((size_t)Etot * 4);
    int* rowst   = (int*)carve((size_t)(NN + 1) * 4);
    int* srcs    = (int*)carve((size_t)Etot * 4);
    unsigned int* ebuf = (unsigned int*)carve((size_t)Etot * 4);
    int* bcount  = (int*)carve((size_t)NBUK * 4);
    int* bbase   = (int*)carve((size_t)(NBUK + 1) * 4);
    int* bcursor = (int*)carve((size_t)NBUK * 4);

    // ---- CSR build via buckets ----
    hipMemsetAsync(bcount, 0, (size_t)NBUK * 4, stream);
    bucket_count<<<256, 256, 0, stream>>>(dst_arr, bcount, Etot, E);
    bucket_scan<<<1, 256, 0, stream>>>(bcount, bbase, bcursor, rowst, Etot);
    bucket_scatter<<<256, 256, 0, stream>>>(src_arr, dst_arr, bcursor, ebuf, Etot, E);
    bucket_csr<<<NBUK, 256, 0, stream>>>(ebuf, bbase, rowst, srcs);

    // ---- weights prep ----
    cvt_weights<<<144, 256, 0, stream>>>(W1, W2, w1t, w2b);

    // ---- layer 1 ----
    gemm1_mfma<<<(NN + 63) / 64, 256, 0, stream>>>(x, w1t, h1b, NN);
    scores1_kernel<<<NN / 4, 256, 0, stream>>>(h1b, a_src1, a_dst1, ssrc1, sdst1);
    agg1a_kernel<<<NN / 4, 256, 0, stream>>>(ssrc1, sdst1, rowst, srcs, alpha1);
    agg1b_kernel<<<NN / 4, 256, 0, stream>>>(h1b, alpha1, rowst, srcs, b1, out1b);

    // ---- layer 2 ----
    gemm2_mfma<<<(NN + 63) / 64, 256, 0, stream>>>(out1b, w2b, a_src2, a_dst2,
                                                   h2, ssrc2, sdst2, NN);
    agg2a_kernel<<<NN / 4, 256, 0, stream>>>(ssrc2, sdst2, rowst, srcs, alpha2);
    agg2b_kernel<<<NN / 4, 256, 0, stream>>>(h2, alpha2, rowst, srcs, b2, out);
}

// Round 7
// 173.055 us; speedup vs baseline: 3.1429x; 1.1014x over previous
//
#include <hip/hip_runtime.h>
#include <cstdint>
#include <cstddef>

#define NN 50000
#define IN_CH 128
#define C1 256        // HEADS*HID
#define HID 64
#define HEADS 4
#define OUT_CH 16
#define NEG_SLOPE 0.2f
#define EPS_SM 1e-16f
#define NEGINF -3.4e38f
#define NBUK ((NN + 255) >> 8)   // 196 buckets of 256 dst nodes

typedef __attribute__((ext_vector_type(8))) short bf16x8;
typedef __attribute__((ext_vector_type(4))) float f32x4;

__device__ __forceinline__ unsigned short f2b(float f) {
    unsigned int u = __float_as_uint(f);
    u += 0x7fffu + ((u >> 16) & 1u);   // round-to-nearest-even
    return (unsigned short)(u >> 16);
}
__device__ __forceinline__ float b2f_lo(unsigned int packed) {
    return __uint_as_float(packed << 16);
}
__device__ __forceinline__ float b2f_hi(unsigned int packed) {
    return __uint_as_float(packed & 0xffff0000u);
}

// -------- weight prep: w1t[n][k] bf16 (n-major), w2b[c][k] bf16 ------------
__global__ void cvt_weights(const float* __restrict__ W1, const float* __restrict__ W2,
                            unsigned short* __restrict__ w1t, unsigned short* __restrict__ w2b) {
    int b = blockIdx.x, t = threadIdx.x;
    if (b < 128) {
        w1t[t * 128 + b] = f2b(W1[b * 256 + t]);
    } else {
        int k = (b - 128) * 16 + (t >> 4);
        int c = t & 15;
        w2b[c * 256 + k] = f2b(W2[k * 16 + c]);
    }
}

// ------- GEMM1 (MFMA bf16) + fused per-head scores --------------------------
// wave wv owns cols wv*64..wv*64+63 == head wv exactly.
__global__ __launch_bounds__(256) void gemm1_mfma(const float* __restrict__ X,
                                                  const unsigned short* __restrict__ w1t,
                                                  const float* __restrict__ a_src1,
                                                  const float* __restrict__ a_dst1,
                                                  unsigned short* __restrict__ h1b,
                                                  float* __restrict__ ssrc1,
                                                  float* __restrict__ sdst1, int M) {
    __shared__ unsigned short xb[64 * 128];    // 16KB, swizzled
    __shared__ unsigned short wt[256 * 128];   // 64KB, swizzled (w1t staged)
    int tid = threadIdx.x;
    int m0 = blockIdx.x * 64;
    {
        const uint4* gp = (const uint4*)w1t;
#pragma unroll
        for (int r = 0; r < 16; ++r) {
            int idx = r * 256 + tid;
            int byte = idx * 16;
            int row = byte >> 8;
            int cb = byte & 255;
            uint4 v = gp[idx];
            *(uint4*)((char*)wt + row * 256 + (cb ^ ((row & 7) << 4))) = v;
        }
    }
    {
#pragma unroll
        for (int r = 0; r < 8; ++r) {
            int f = r * 256 + tid;   // float4 index
            int e = f * 4;
            int row = e >> 7, col = e & 127;
            float4 v = make_float4(0.f, 0.f, 0.f, 0.f);
            if (m0 + row < M) v = *(const float4*)&X[(size_t)(m0 + row) * 128 + col];
            ushort4 bb;
            bb.x = f2b(v.x); bb.y = f2b(v.y); bb.z = f2b(v.z); bb.w = f2b(v.w);
            *(ushort4*)((char*)xb + row * 256 + ((col * 2) ^ ((row & 7) << 4))) = bb;
        }
    }
    __syncthreads();
    int wv = tid >> 6, l = tid & 63;
    int lm = l & 15, lk = l >> 4;
    int swz = (lm & 7) << 4;
    f32x4 acc[4][4];
#pragma unroll
    for (int a = 0; a < 4; ++a)
#pragma unroll
        for (int b = 0; b < 4; ++b) acc[a][b] = (f32x4){0.f, 0.f, 0.f, 0.f};
#pragma unroll
    for (int kk = 0; kk < 4; ++kk) {
        int kb = (kk * 64 + lk * 16) ^ swz;
        bf16x8 af[4], bfr[4];
#pragma unroll
        for (int mf = 0; mf < 4; ++mf)
            af[mf] = *(const bf16x8*)((const char*)xb + (mf * 16 + lm) * 256 + kb);
#pragma unroll
        for (int nt = 0; nt < 4; ++nt)
            bfr[nt] = *(const bf16x8*)((const char*)wt + (wv * 64 + nt * 16 + lm) * 256 + kb);
#pragma unroll
        for (int mf = 0; mf < 4; ++mf)
#pragma unroll
            for (int nt = 0; nt < 4; ++nt)
                acc[mf][nt] = __builtin_amdgcn_mfma_f32_16x16x32_bf16(af[mf], bfr[nt], acc[mf][nt], 0, 0, 0);
    }
    // store h1b
#pragma unroll
    for (int mf = 0; mf < 4; ++mf) {
#pragma unroll
        for (int r = 0; r < 4; ++r) {
            int row = m0 + mf * 16 + lk * 4 + r;
            if (row < M) {
#pragma unroll
                for (int nt = 0; nt < 4; ++nt)
                    h1b[(size_t)row * 256 + wv * 64 + nt * 16 + lm] = f2b(acc[mf][nt][r]);
            }
        }
    }
    // fused scores for head wv
    float av[4], dv[4];
#pragma unroll
    for (int nt = 0; nt < 4; ++nt) {
        av[nt] = a_src1[wv * 64 + nt * 16 + lm];
        dv[nt] = a_dst1[wv * 64 + nt * 16 + lm];
    }
#pragma unroll
    for (int mf = 0; mf < 4; ++mf) {
#pragma unroll
        for (int r = 0; r < 4; ++r) {
            float ps = acc[mf][0][r] * av[0] + acc[mf][1][r] * av[1]
                     + acc[mf][2][r] * av[2] + acc[mf][3][r] * av[3];
            float pd = acc[mf][0][r] * dv[0] + acc[mf][1][r] * dv[1]
                     + acc[mf][2][r] * dv[2] + acc[mf][3][r] * dv[3];
#pragma unroll
            for (int o = 1; o < 16; o <<= 1) {
                ps += __shfl_xor(ps, o);
                pd += __shfl_xor(pd, o);
            }
            if (lm == 0) {
                int row = m0 + mf * 16 + lk * 4 + r;
                if (row < M) {
                    ssrc1[row * HEADS + wv] = ps;
                    sdst1[row * HEADS + wv] = pd;
                }
            }
        }
    }
}

// ================= CSR build via dst-buckets (196 x 256 nodes) =============
__global__ __launch_bounds__(256) void bucket_count(const int* __restrict__ dst_arr,
                                                    int* __restrict__ bcount,
                                                    int Etot, int E) {
    __shared__ int cnt[NBUK];
    int t = threadIdx.x;
    for (int i = t; i < NBUK; i += 256) cnt[i] = 0;
    __syncthreads();
    for (int i = blockIdx.x * 256 + t; i < Etot; i += gridDim.x * 256) {
        int dst = (i < E) ? dst_arr[i] : (i - E);
        atomicAdd(&cnt[dst >> 8], 1);
    }
    __syncthreads();
    for (int i = t; i < NBUK; i += 256)
        if (cnt[i]) atomicAdd(&bcount[i], cnt[i]);
}

__global__ __launch_bounds__(256) void bucket_scan(const int* __restrict__ bcount,
                                                   int* __restrict__ bbase,
                                                   int* __restrict__ bcursor,
                                                   int* __restrict__ rowst, int Etot) {
    __shared__ int s[256];
    int t = threadIdx.x;
    int x = (t < NBUK) ? bcount[t] : 0;
    s[t] = x;
    __syncthreads();
    for (int off = 1; off < 256; off <<= 1) {
        int v = (t >= off) ? s[t - off] : 0;
        __syncthreads();
        s[t] += v;
        __syncthreads();
    }
    int excl = s[t] - x;
    if (t < NBUK) {
        bbase[t] = excl;
        bcursor[t] = excl;
    }
    if (t == 0) {
        bbase[NBUK] = Etot;
        rowst[NN] = Etot;
    }
}

__global__ __launch_bounds__(256) void bucket_scatter(const int* __restrict__ src_arr,
                                                      const int* __restrict__ dst_arr,
                                                      int* __restrict__ bcursor,
                                                      unsigned int* __restrict__ ebuf,
                                                      int Etot, int E) {
    __shared__ int cnt[NBUK];
    __shared__ int cur[NBUK];
    int t = threadIdx.x;
    for (int i = t; i < NBUK; i += 256) cnt[i] = 0;
    __syncthreads();
    for (int i = blockIdx.x * 256 + t; i < Etot; i += gridDim.x * 256) {
        int dst = (i < E) ? dst_arr[i] : (i - E);
        atomicAdd(&cnt[dst >> 8], 1);
    }
    __syncthreads();
    for (int i = t; i < NBUK; i += 256)
        cur[i] = cnt[i] ? atomicAdd(&bcursor[i], cnt[i]) : 0;
    __syncthreads();
    for (int i = blockIdx.x * 256 + t; i < Etot; i += gridDim.x * 256) {
        int dst, src;
        if (i < E) { dst = dst_arr[i]; src = src_arr[i]; }
        else { dst = i - E; src = i - E; }
        int pos = atomicAdd(&cur[dst >> 8], 1);
        ebuf[pos] = ((unsigned int)(dst & 255) << 16) | (unsigned int)src;
    }
}

__global__ __launch_bounds__(256) void bucket_csr(const unsigned int* __restrict__ ebuf,
                                                  const int* __restrict__ bbase,
                                                  int* __restrict__ rowst,
                                                  int* __restrict__ srcs) {
    __shared__ int sdeg[256];
    __shared__ int scur[256];
    int t = threadIdx.x, b = blockIdx.x;
    int ebase = bbase[b], eend = bbase[b + 1];
    sdeg[t] = 0;
    __syncthreads();
    for (int i = ebase + t; i < eend; i += 256)
        atomicAdd(&sdeg[ebuf[i] >> 16], 1);
    __syncthreads();
    int x = sdeg[t];
    __syncthreads();
    for (int off = 1; off < 256; off <<= 1) {
        int v = (t >= off) ? sdeg[t - off] : 0;
        __syncthreads();
        sdeg[t] += v;
        __syncthreads();
    }
    int excl = sdeg[t] - x;
    int gnode = b * 256 + t;
    if (gnode < NN) rowst[gnode] = ebase + excl;
    scur[t] = excl;
    __syncthreads();
    for (int i = ebase + t; i < eend; i += 256) {
        unsigned int e = ebuf[i];
        int pos = atomicAdd(&scur[e >> 16], 1);
        srcs[ebase + pos] = (int)(e & 0xffffu);
    }
}

// ------- fused layer-1: softmax (phase A) + gather/ELU (phase B) -----------
__global__ __launch_bounds__(256) void agg1_fused(const unsigned short* __restrict__ h1b,
                                                  const float* __restrict__ ssrc1,
                                                  const float* __restrict__ sdst1,
                                                  const int* __restrict__ row_start,
                                                  const int* __restrict__ srcs,
                                                  const float* __restrict__ b1,
                                                  unsigned short* __restrict__ out1b) {
    int d = blockIdx.x * 4 + (threadIdx.x >> 6);
    int l = threadIdx.x & 63;
    int start = row_start[d], end = row_start[d + 1];

    // ---- phase A: per-head running max+sum (16 slots x 4 heads)
    int sub = l & 15, h = l >> 4;
    float sdstA = sdst1[d * HEADS + h];
    auto comp = [&](int i) -> float {
        int s = srcs[i];
        float e = ssrc1[s * HEADS + h] + sdstA;
        return e > 0.f ? e : NEG_SLOPE * e;
    };
    float e0 = NEGINF, e1 = NEGINF, e2 = NEGINF, e3 = NEGINF;
    int i0 = start + sub;
    if (i0 < end) e0 = comp(i0);
    if (i0 + 16 < end) e1 = comp(i0 + 16);
    if (i0 + 32 < end) e2 = comp(i0 + 32);
    if (i0 + 48 < end) e3 = comp(i0 + 48);
    float mx = fmaxf(fmaxf(e0, e1), fmaxf(e2, e3));
    for (int i = i0 + 64; i < end; i += 16) mx = fmaxf(mx, comp(i));
#pragma unroll
    for (int o = 1; o < 16; o <<= 1) mx = fmaxf(mx, __shfl_xor(mx, o));
    float ssum = __expf(e0 - mx) + __expf(e1 - mx) + __expf(e2 - mx) + __expf(e3 - mx);
    for (int i = i0 + 64; i < end; i += 16) ssum += __expf(comp(i) - mx);
#pragma unroll
    for (int o = 1; o < 16; o <<= 1) ssum += __shfl_xor(ssum, o);
    float inv = 1.f / (ssum + EPS_SM);

    // ---- phase B: gather, 2 edge-slots x 32 channel-lanes, alpha inline
    int half = l >> 5;
    int cl = l & 31;
    int hc = cl >> 3;
    float mxB = __shfl(mx, hc << 4);
    float invB = __shfl(inv, hc << 4);
    float sdstB = __shfl(sdstA, hc << 4);
    const int cb = cl * 8;
    auto alphaB = [&](int s) -> float {
        float e = ssrc1[s * HEADS + hc] + sdstB;
        e = e > 0.f ? e : NEG_SLOPE * e;
        return __expf(e - mxB) * invB;
    };
    float acc[8] = {};
    int i = start + half;
    for (; i + 6 < end; i += 8) {
        int s0 = srcs[i], s1 = srcs[i + 2], s2 = srcs[i + 4], s3 = srcs[i + 6];
        uint4 v0 = *(const uint4*)&h1b[(size_t)s0 * C1 + cb];
        uint4 v1 = *(const uint4*)&h1b[(size_t)s1 * C1 + cb];
        uint4 v2 = *(const uint4*)&h1b[(size_t)s2 * C1 + cb];
        uint4 v3 = *(const uint4*)&h1b[(size_t)s3 * C1 + cb];
        float a0 = alphaB(s0), a1 = alphaB(s1), a2 = alphaB(s2), a3 = alphaB(s3);
        acc[0] += a0 * b2f_lo(v0.x) + a1 * b2f_lo(v1.x) + a2 * b2f_lo(v2.x) + a3 * b2f_lo(v3.x);
        acc[1] += a0 * b2f_hi(v0.x) + a1 * b2f_hi(v1.x) + a2 * b2f_hi(v2.x) + a3 * b2f_hi(v3.x);
        acc[2] += a0 * b2f_lo(v0.y) + a1 * b2f_lo(v1.y) + a2 * b2f_lo(v2.y) + a3 * b2f_lo(v3.y);
        acc[3] += a0 * b2f_hi(v0.y) + a1 * b2f_hi(v1.y) + a2 * b2f_hi(v2.y) + a3 * b2f_hi(v3.y);
        acc[4] += a0 * b2f_lo(v0.z) + a1 * b2f_lo(v1.z) + a2 * b2f_lo(v2.z) + a3 * b2f_lo(v3.z);
        acc[5] += a0 * b2f_hi(v0.z) + a1 * b2f_hi(v1.z) + a2 * b2f_hi(v2.z) + a3 * b2f_hi(v3.z);
        acc[6] += a0 * b2f_lo(v0.w) + a1 * b2f_lo(v1.w) + a2 * b2f_lo(v2.w) + a3 * b2f_lo(v3.w);
        acc[7] += a0 * b2f_hi(v0.w) + a1 * b2f_hi(v1.w) + a2 * b2f_hi(v2.w) + a3 * b2f_hi(v3.w);
    }
    for (; i < end; i += 2) {
        int s = srcs[i];
        uint4 v = *(const uint4*)&h1b[(size_t)s * C1 + cb];
        float a = alphaB(s);
        acc[0] += a * b2f_lo(v.x); acc[1] += a * b2f_hi(v.x);
        acc[2] += a * b2f_lo(v.y); acc[3] += a * b2f_hi(v.y);
        acc[4] += a * b2f_lo(v.z); acc[5] += a * b2f_hi(v.z);
        acc[6] += a * b2f_lo(v.w); acc[7] += a * b2f_hi(v.w);
    }
#pragma unroll
    for (int j = 0; j < 8; ++j) acc[j] += __shfl_xor(acc[j], 32);
    if (half == 0) {
        float4 ba = *(const float4*)&b1[cb];
        float4 bbv = *(const float4*)&b1[cb + 4];
        float v[8];
        v[0] = acc[0] + ba.x;  v[1] = acc[1] + ba.y;
        v[2] = acc[2] + ba.z;  v[3] = acc[3] + ba.w;
        v[4] = acc[4] + bbv.x; v[5] = acc[5] + bbv.y;
        v[6] = acc[6] + bbv.z; v[7] = acc[7] + bbv.w;
        bf16x8 o;
#pragma unroll
        for (int j = 0; j < 8; ++j) {
            float t = v[j] > 0.f ? v[j] : (__expf(v[j]) - 1.f);
            o[j] = (short)f2b(t);
        }
        *(bf16x8*)&out1b[(size_t)d * C1 + cb] = o;
    }
}

// ------- GEMM2 (MFMA): h2[N,16] = out1b[N,256] @ W2b  + fused scores -------
__global__ __launch_bounds__(256) void gemm2_mfma(const unsigned short* __restrict__ out1b,
                                                  const unsigned short* __restrict__ w2b,
                                                  const float* __restrict__ a_src2,
                                                  const float* __restrict__ a_dst2,
                                                  float* __restrict__ h2,
                                                  float* __restrict__ ssrc2,
                                                  float* __restrict__ sdst2, int M) {
    __shared__ char ab[64 * 528];
    int tid = threadIdx.x;
    int m0 = blockIdx.x * 64;
#pragma unroll
    for (int r = 0; r < 8; ++r) {
        int byte = r * 4096 + tid * 16;
        int row = byte >> 9, col = byte & 511;
        uint4 v = make_uint4(0u, 0u, 0u, 0u);
        if (m0 + row < M)
            v = *(const uint4*)((const char*)out1b + (size_t)(m0 + row) * 512 + col);
        *(uint4*)(ab + row * 528 + col) = v;
    }
    int wv = tid >> 6, l = tid & 63;
    int lm = l & 15, lk = l >> 4;
    bf16x8 bfr[8];
#pragma unroll
    for (int kk = 0; kk < 8; ++kk)
        bfr[kk] = *(const bf16x8*)&w2b[lm * 256 + lk * 8 + kk * 32];
    __syncthreads();
    f32x4 acc = (f32x4){0.f, 0.f, 0.f, 0.f};
    const char* base = ab + (wv * 16 + lm) * 528 + lk * 16;
#pragma unroll
    for (int kk = 0; kk < 8; ++kk) {
        bf16x8 af = *(const bf16x8*)(base + kk * 64);
        acc = __builtin_amdgcn_mfma_f32_16x16x32_bf16(af, bfr[kk], acc, 0, 0, 0);
    }
    float asc = a_src2[lm], adc = a_dst2[lm];
#pragma unroll
    for (int r = 0; r < 4; ++r) {
        int grow = m0 + wv * 16 + lk * 4 + r;
        float v = acc[r];
        float ps = v * asc, pd = v * adc;
#pragma unroll
        for (int o = 1; o < 16; o <<= 1) {
            ps += __shfl_xor(ps, o);
            pd += __shfl_xor(pd, o);
        }
        if (grow < M) {
            h2[(size_t)grow * OUT_CH + lm] = v;
            if (lm == 0) {
                ssrc2[grow] = ps;
                sdst2[grow] = pd;
            }
        }
    }
}

// ------- fused layer-2: softmax (phase A) + gather + bias (phase B) --------
__global__ __launch_bounds__(256) void agg2_fused(const float* __restrict__ h2,
                                                  const float* __restrict__ ssrc2,
                                                  const float* __restrict__ sdst2,
                                                  const int* __restrict__ row_start,
                                                  const int* __restrict__ srcs,
                                                  const float* __restrict__ b2,
                                                  float* __restrict__ out) {
    int d = blockIdx.x * 4 + (threadIdx.x >> 6);
    int l = threadIdx.x & 63;
    int start = row_start[d], end = row_start[d + 1];
    float sdst = sdst2[d];
    auto comp = [&](int i) -> float {
        int s = srcs[i];
        float e = ssrc2[s] + sdst;
        return e > 0.f ? e : NEG_SLOPE * e;
    };
    // phase A: online max+sum, 64 slots
    float e0 = NEGINF, e1 = NEGINF;
    int i0 = start + l;
    if (i0 < end) e0 = comp(i0);
    if (i0 + 64 < end) e1 = comp(i0 + 64);
    float mx = fmaxf(e0, e1);
    for (int i = i0 + 128; i < end; i += 64) mx = fmaxf(mx, comp(i));
#pragma unroll
    for (int o = 1; o < 64; o <<= 1) mx = fmaxf(mx, __shfl_xor(mx, o));
    float ssum = __expf(e0 - mx) + __expf(e1 - mx);
    for (int i = i0 + 128; i < end; i += 64) ssum += __expf(comp(i) - mx);
#pragma unroll
    for (int o = 1; o < 64; o <<= 1) ssum += __shfl_xor(ssum, o);
    float inv = 1.f / (ssum + EPS_SM);

    // phase B: 16 edge-slots x 4 lanes, float4 gathers, alpha inline
    int slot = l >> 2;
    int c4 = (l & 3) * 4;
    float4 acc = make_float4(0.f, 0.f, 0.f, 0.f);
    for (int i = start + slot; i < end; i += 16) {
        int s = srcs[i];
        float e = ssrc2[s] + sdst;
        e = e > 0.f ? e : NEG_SLOPE * e;
        float a = __expf(e - mx) * inv;
        float4 v = *(const float4*)&h2[(size_t)s * OUT_CH + c4];
        acc.x += a * v.x; acc.y += a * v.y; acc.z += a * v.z; acc.w += a * v.w;
    }
#pragma unroll
    for (int o = 4; o < 64; o <<= 1) {
        acc.x += __shfl_xor(acc.x, o);
        acc.y += __shfl_xor(acc.y, o);
        acc.z += __shfl_xor(acc.z, o);
        acc.w += __shfl_xor(acc.w, o);
    }
    if (l < 4) {
        float4 bb = *(const float4*)&b2[c4];
        float4 r = make_float4(acc.x + bb.x, acc.y + bb.y, acc.z + bb.z, acc.w + bb.w);
        *(float4*)&out[(size_t)d * OUT_CH + c4] = r;
    }
}

extern "C" void kernel_launch(void* const* d_in, const int* in_sizes, int n_in,
                              void* d_out, int out_size, void* d_ws, size_t ws_size,
                              hipStream_t stream) {
    const float* x      = (const float*)d_in[0];
    const int*   ei     = (const int*)d_in[1];
    const float* W1     = (const float*)d_in[2];
    const float* a_src1 = (const float*)d_in[3];
    const float* a_dst1 = (const float*)d_in[4];
    const float* b1     = (const float*)d_in[5];
    const float* W2     = (const float*)d_in[6];
    const float* a_src2 = (const float*)d_in[7];
    const float* a_dst2 = (const float*)d_in[8];
    const float* b2     = (const float*)d_in[9];
    float* out = (float*)d_out;

    const int E = in_sizes[1] / 2;
    const int Etot = E + NN;
    const int* src_arr = ei;
    const int* dst_arr = ei + E;

    size_t off = 0;
    auto carve = [&](size_t bytes) -> void* {
        void* r = (char*)d_ws + off;
        off += (bytes + 255) & ~(size_t)255;
        return r;
    };
    unsigned short* h1b  = (unsigned short*)carve((size_t)NN * C1 * 2);
    unsigned short* out1b= (unsigned short*)carve((size_t)NN * C1 * 2);
    unsigned short* w1t  = (unsigned short*)carve((size_t)IN_CH * C1 * 2);
    unsigned short* w2b  = (unsigned short*)carve((size_t)C1 * OUT_CH * 2);
    float* ssrc1 = (float*)carve((size_t)NN * HEADS * 4);
    float* sdst1 = (float*)carve((size_t)NN * HEADS * 4);
    float* h2    = (float*)carve((size_t)NN * OUT_CH * 4);
    float* ssrc2 = (float*)carve((size_t)NN * 4);
    float* sdst2 = (float*)carve((size_t)NN * 4);
    int* rowst   = (int*)carve((size_t)(NN + 1) * 4);
    int* srcs    = (int*)carve((size_t)Etot * 4);
    unsigned int* ebuf = (unsigned int*)carve((size_t)Etot * 4);
    int* bcount  = (int*)carve((size_t)NBUK * 4);
    int* bbase   = (int*)carve((size_t)(NBUK + 1) * 4);
    int* bcursor = (int*)carve((size_t)NBUK * 4);

    // ---- CSR build via buckets ----
    hipMemsetAsync(bcount, 0, (size_t)NBUK * 4, stream);
    bucket_count<<<256, 256, 0, stream>>>(dst_arr, bcount, Etot, E);
    bucket_scan<<<1, 256, 0, stream>>>(bcount, bbase, bcursor, rowst, Etot);
    bucket_scatter<<<256, 256, 0, stream>>>(src_arr, dst_arr, bcursor, ebuf, Etot, E);
    bucket_csr<<<NBUK, 256, 0, stream>>>(ebuf, bbase, rowst, srcs);

    // ---- weights prep ----
    cvt_weights<<<144, 256, 0, stream>>>(W1, W2, w1t, w2b);

    // ---- layer 1 ----
    gemm1_mfma<<<(NN + 63) / 64, 256, 0, stream>>>(x, w1t, a_src1, a_dst1,
                                                   h1b, ssrc1, sdst1, NN);
    agg1_fused<<<NN / 4, 256, 0, stream>>>(h1b, ssrc1, sdst1, rowst, srcs, b1, out1b);

    // ---- layer 2 ----
    gemm2_mfma<<<(NN + 63) / 64, 256, 0, stream>>>(out1b, w2b, a_src2, a_dst2,
                                                   h2, ssrc2, sdst2, NN);
    agg2_fused<<<NN / 4, 256, 0, stream>>>(h2, ssrc2, sdst2, rowst, srcs, b2, out);
}

// Round 8
// 171.577 us; speedup vs baseline: 3.1700x; 1.0086x over previous
//
#include <hip/hip_runtime.h>
#include <cstdint>
#include <cstddef>

#define NN 50000
#define IN_CH 128
#define C1 256        // HEADS*HID
#define HID 64
#define HEADS 4
#define OUT_CH 16
#define NEG_SLOPE 0.2f
#define EPS_SM 1e-16f
#define NEGINF -3.4e38f
#define NBUK ((NN + 255) >> 8)   // 196 buckets of 256 dst nodes

typedef __attribute__((ext_vector_type(8))) short bf16x8;
typedef __attribute__((ext_vector_type(4))) float f32x4;

__device__ __forceinline__ unsigned short f2b(float f) {
    unsigned int u = __float_as_uint(f);
    u += 0x7fffu + ((u >> 16) & 1u);   // round-to-nearest-even
    return (unsigned short)(u >> 16);
}
__device__ __forceinline__ float b2f_lo(unsigned int packed) {
    return __uint_as_float(packed << 16);
}
__device__ __forceinline__ float b2f_hi(unsigned int packed) {
    return __uint_as_float(packed & 0xffff0000u);
}

// -------- weight prep: w1t[n][k] bf16, w2b[c][k] bf16, waSDt[16][128] bf16 --
// waSDt col c<4: (W1·a_src1_head_c); col 4..7: (W1·a_dst1_head_{c-4}); 8..15: 0
__global__ void cvt_weights(const float* __restrict__ W1, const float* __restrict__ W2,
                            const float* __restrict__ a_src1, const float* __restrict__ a_dst1,
                            unsigned short* __restrict__ w1t, unsigned short* __restrict__ w2b,
                            unsigned short* __restrict__ waSDt) {
    int b = blockIdx.x, t = threadIdx.x;
    if (b < 128) {
        w1t[t * 128 + b] = f2b(W1[b * 256 + t]);
    } else if (b < 144) {
        int k = (b - 128) * 16 + (t >> 4);
        int c = t & 15;
        w2b[c * 256 + k] = f2b(W2[k * 16 + c]);
    } else {
        // score-weight GEMV: one thread per k (<128)
        if (t < 128) {
            const float* wrow = W1 + t * 256;
#pragma unroll
            for (int h = 0; h < 4; ++h) {
                float ss = 0.f, sd = 0.f;
#pragma unroll
                for (int c = 0; c < 64; ++c) {
                    float w = wrow[h * 64 + c];
                    ss += w * a_src1[h * 64 + c];
                    sd += w * a_dst1[h * 64 + c];
                }
                waSDt[h * 128 + t] = f2b(ss);
                waSDt[(4 + h) * 128 + t] = f2b(sd);
            }
#pragma unroll
            for (int c = 8; c < 16; ++c) waSDt[c * 128 + t] = 0;
        }
    }
}

// ------- GEMM1 (MFMA bf16) + MFMA-based fused scores ------------------------
__global__ __launch_bounds__(256) void gemm1_mfma(const float* __restrict__ X,
                                                  const unsigned short* __restrict__ w1t,
                                                  const unsigned short* __restrict__ waSDt,
                                                  unsigned short* __restrict__ h1b,
                                                  float* __restrict__ ssrc1,
                                                  float* __restrict__ sdst1, int M) {
    __shared__ unsigned short xb[64 * 128];    // 16KB, swizzled
    __shared__ unsigned short wt[256 * 128];   // 64KB, swizzled (w1t staged)
    int tid = threadIdx.x;
    int m0 = blockIdx.x * 64;
    {
        const uint4* gp = (const uint4*)w1t;
#pragma unroll
        for (int r = 0; r < 16; ++r) {
            int idx = r * 256 + tid;
            int byte = idx * 16;
            int row = byte >> 8;
            int cb = byte & 255;
            uint4 v = gp[idx];
            *(uint4*)((char*)wt + row * 256 + (cb ^ ((row & 7) << 4))) = v;
        }
    }
    {
#pragma unroll
        for (int r = 0; r < 8; ++r) {
            int f = r * 256 + tid;   // float4 index
            int e = f * 4;
            int row = e >> 7, col = e & 127;
            float4 v = make_float4(0.f, 0.f, 0.f, 0.f);
            if (m0 + row < M) v = *(const float4*)&X[(size_t)(m0 + row) * 128 + col];
            ushort4 bb;
            bb.x = f2b(v.x); bb.y = f2b(v.y); bb.z = f2b(v.z); bb.w = f2b(v.w);
            *(ushort4*)((char*)xb + row * 256 + ((col * 2) ^ ((row & 7) << 4))) = bb;
        }
    }
    __syncthreads();
    int wv = tid >> 6, l = tid & 63;
    int lm = l & 15, lk = l >> 4;
    int swz = (lm & 7) << 4;
    // preload score B-fragments (4KB, L2-hot)
    bf16x8 sfr[4];
#pragma unroll
    for (int kk = 0; kk < 4; ++kk)
        sfr[kk] = *(const bf16x8*)&waSDt[lm * 128 + kk * 32 + lk * 8];
    f32x4 acc[4][4];
    f32x4 accS[4];
#pragma unroll
    for (int a = 0; a < 4; ++a) {
        accS[a] = (f32x4){0.f, 0.f, 0.f, 0.f};
#pragma unroll
        for (int b = 0; b < 4; ++b) acc[a][b] = (f32x4){0.f, 0.f, 0.f, 0.f};
    }
#pragma unroll
    for (int kk = 0; kk < 4; ++kk) {
        int kb = (kk * 64 + lk * 16) ^ swz;
        bf16x8 af[4], bfr[4];
#pragma unroll
        for (int mf = 0; mf < 4; ++mf)
            af[mf] = *(const bf16x8*)((const char*)xb + (mf * 16 + lm) * 256 + kb);
#pragma unroll
        for (int nt = 0; nt < 4; ++nt)
            bfr[nt] = *(const bf16x8*)((const char*)wt + (wv * 64 + nt * 16 + lm) * 256 + kb);
#pragma unroll
        for (int mf = 0; mf < 4; ++mf) {
#pragma unroll
            for (int nt = 0; nt < 4; ++nt)
                acc[mf][nt] = __builtin_amdgcn_mfma_f32_16x16x32_bf16(af[mf], bfr[nt], acc[mf][nt], 0, 0, 0);
            accS[mf] = __builtin_amdgcn_mfma_f32_16x16x32_bf16(af[mf], sfr[kk], accS[mf], 0, 0, 0);
        }
    }
    // store h1b
#pragma unroll
    for (int mf = 0; mf < 4; ++mf) {
#pragma unroll
        for (int r = 0; r < 4; ++r) {
            int row = m0 + mf * 16 + lk * 4 + r;
            if (row < M) {
#pragma unroll
                for (int nt = 0; nt < 4; ++nt)
                    h1b[(size_t)row * 256 + wv * 64 + nt * 16 + lm] = f2b(acc[mf][nt][r]);
            }
        }
    }
    // scores: wave wv writes rows of its own mf = wv (C layout: col=lm, row=lk*4+r)
    {
        f32x4 as = accS[wv];
#pragma unroll
        for (int r = 0; r < 4; ++r) {
            int row = m0 + wv * 16 + lk * 4 + r;
            if (row < M && lm < 8) {
                if (lm < 4) ssrc1[row * HEADS + lm] = as[r];
                else        sdst1[row * HEADS + (lm - 4)] = as[r];
            }
        }
    }
}

// ================= CSR build via dst-buckets (196 x 256 nodes) =============
__global__ __launch_bounds__(256) void bucket_count(const int* __restrict__ dst_arr,
                                                    int* __restrict__ bcount,
                                                    int Etot, int E) {
    __shared__ int cnt[NBUK];
    int t = threadIdx.x;
    for (int i = t; i < NBUK; i += 256) cnt[i] = 0;
    __syncthreads();
    for (int i = blockIdx.x * 256 + t; i < Etot; i += gridDim.x * 256) {
        int dst = (i < E) ? dst_arr[i] : (i - E);
        atomicAdd(&cnt[dst >> 8], 1);
    }
    __syncthreads();
    for (int i = t; i < NBUK; i += 256)
        if (cnt[i]) atomicAdd(&bcount[i], cnt[i]);
}

__global__ __launch_bounds__(256) void bucket_scan(const int* __restrict__ bcount,
                                                   int* __restrict__ bbase,
                                                   int* __restrict__ bcursor,
                                                   int* __restrict__ rowst, int Etot) {
    __shared__ int s[256];
    int t = threadIdx.x;
    int x = (t < NBUK) ? bcount[t] : 0;
    s[t] = x;
    __syncthreads();
    for (int off = 1; off < 256; off <<= 1) {
        int v = (t >= off) ? s[t - off] : 0;
        __syncthreads();
        s[t] += v;
        __syncthreads();
    }
    int excl = s[t] - x;
    if (t < NBUK) {
        bbase[t] = excl;
        bcursor[t] = excl;
    }
    if (t == 0) {
        bbase[NBUK] = Etot;
        rowst[NN] = Etot;
    }
}

__global__ __launch_bounds__(256) void bucket_scatter(const int* __restrict__ src_arr,
                                                      const int* __restrict__ dst_arr,
                                                      int* __restrict__ bcursor,
                                                      unsigned int* __restrict__ ebuf,
                                                      int Etot, int E) {
    __shared__ int cnt[NBUK];
    __shared__ int cur[NBUK];
    int t = threadIdx.x;
    for (int i = t; i < NBUK; i += 256) cnt[i] = 0;
    __syncthreads();
    for (int i = blockIdx.x * 256 + t; i < Etot; i += gridDim.x * 256) {
        int dst = (i < E) ? dst_arr[i] : (i - E);
        atomicAdd(&cnt[dst >> 8], 1);
    }
    __syncthreads();
    for (int i = t; i < NBUK; i += 256)
        cur[i] = cnt[i] ? atomicAdd(&bcursor[i], cnt[i]) : 0;
    __syncthreads();
    for (int i = blockIdx.x * 256 + t; i < Etot; i += gridDim.x * 256) {
        int dst, src;
        if (i < E) { dst = dst_arr[i]; src = src_arr[i]; }
        else { dst = i - E; src = i - E; }
        int pos = atomicAdd(&cur[dst >> 8], 1);
        ebuf[pos] = ((unsigned int)(dst & 255) << 16) | (unsigned int)src;
    }
}

__global__ __launch_bounds__(256) void bucket_csr(const unsigned int* __restrict__ ebuf,
                                                  const int* __restrict__ bbase,
                                                  int* __restrict__ rowst,
                                                  int* __restrict__ srcs) {
    __shared__ int sdeg[256];
    __shared__ int scur[256];
    int t = threadIdx.x, b = blockIdx.x;
    int ebase = bbase[b], eend = bbase[b + 1];
    sdeg[t] = 0;
    __syncthreads();
    for (int i = ebase + t; i < eend; i += 256)
        atomicAdd(&sdeg[ebuf[i] >> 16], 1);
    __syncthreads();
    int x = sdeg[t];
    __syncthreads();
    for (int off = 1; off < 256; off <<= 1) {
        int v = (t >= off) ? sdeg[t - off] : 0;
        __syncthreads();
        sdeg[t] += v;
        __syncthreads();
    }
    int excl = sdeg[t] - x;
    int gnode = b * 256 + t;
    if (gnode < NN) rowst[gnode] = ebase + excl;
    scur[t] = excl;
    __syncthreads();
    for (int i = ebase + t; i < eend; i += 256) {
        unsigned int e = ebuf[i];
        int pos = atomicAdd(&scur[e >> 16], 1);
        srcs[ebase + pos] = (int)(e & 0xffffu);
    }
}

// ------- fused layer-1: softmax (A, alpha->LDS) + gather/ELU (B) -----------
__global__ __launch_bounds__(256) void agg1_fused(const unsigned short* __restrict__ h1b,
                                                  const float* __restrict__ ssrc1,
                                                  const float* __restrict__ sdst1,
                                                  const int* __restrict__ row_start,
                                                  const int* __restrict__ srcs,
                                                  const float* __restrict__ b1,
                                                  unsigned short* __restrict__ out1b) {
    __shared__ float alds[4][64][4];   // [wave][edge][head], 4KB
    int wid = threadIdx.x >> 6;
    int d = blockIdx.x * 4 + wid;
    int l = threadIdx.x & 63;
    int start = row_start[d], end = row_start[d + 1];
    int deg = end - start;

    // ---- phase A: per-head max+sum over 16 slots x 4 heads
    int sub = l & 15, h = l >> 4;
    float sdstA = sdst1[d * HEADS + h];
    auto comp = [&](int i) -> float {
        int s = srcs[i];
        float e = ssrc1[s * HEADS + h] + sdstA;
        return e > 0.f ? e : NEG_SLOPE * e;
    };
    float e0 = NEGINF, e1 = NEGINF, e2 = NEGINF, e3 = NEGINF;
    int i0 = start + sub;
    if (i0 < end) e0 = comp(i0);
    if (i0 + 16 < end) e1 = comp(i0 + 16);
    if (i0 + 32 < end) e2 = comp(i0 + 32);
    if (i0 + 48 < end) e3 = comp(i0 + 48);
    float mx = fmaxf(fmaxf(e0, e1), fmaxf(e2, e3));
    for (int i = i0 + 64; i < end; i += 16) mx = fmaxf(mx, comp(i));
#pragma unroll
    for (int o = 1; o < 16; o <<= 1) mx = fmaxf(mx, __shfl_xor(mx, o));
    float s0 = __expf(e0 - mx), s1 = __expf(e1 - mx);
    float s2 = __expf(e2 - mx), s3 = __expf(e3 - mx);
    float ssum = s0 + s1 + s2 + s3;
    for (int i = i0 + 64; i < end; i += 16) ssum += __expf(comp(i) - mx);
#pragma unroll
    for (int o = 1; o < 16; o <<= 1) ssum += __shfl_xor(ssum, o);
    float inv = 1.f / (ssum + EPS_SM);
    // stash alphas (invalid slots store 0 = exp(-inf))
    alds[wid][sub][h] = s0 * inv;
    alds[wid][sub + 16][h] = s1 * inv;
    alds[wid][sub + 32][h] = s2 * inv;
    alds[wid][sub + 48][h] = s3 * inv;
    // wave-synchronous: no barrier needed (same wave writes & reads)

    // ---- phase B: gather, 2 edge-slots x 32 channel-lanes
    int half = l >> 5;
    int cl = l & 31;
    int hc = cl >> 3;
    const int cb = cl * 8;
    float acc[8] = {};
    int i = start + half;
    if (deg <= 64) {
        for (; i + 6 < end; i += 8) {
            int s0_ = srcs[i], s1_ = srcs[i + 2], s2_ = srcs[i + 4], s3_ = srcs[i + 6];
            uint4 v0 = *(const uint4*)&h1b[(size_t)s0_ * C1 + cb];
            uint4 v1 = *(const uint4*)&h1b[(size_t)s1_ * C1 + cb];
            uint4 v2 = *(const uint4*)&h1b[(size_t)s2_ * C1 + cb];
            uint4 v3 = *(const uint4*)&h1b[(size_t)s3_ * C1 + cb];
            float a0 = alds[wid][i - start][hc];
            float a1 = alds[wid][i + 2 - start][hc];
            float a2 = alds[wid][i + 4 - start][hc];
            float a3 = alds[wid][i + 6 - start][hc];
            acc[0] += a0 * b2f_lo(v0.x) + a1 * b2f_lo(v1.x) + a2 * b2f_lo(v2.x) + a3 * b2f_lo(v3.x);
            acc[1] += a0 * b2f_hi(v0.x) + a1 * b2f_hi(v1.x) + a2 * b2f_hi(v2.x) + a3 * b2f_hi(v3.x);
            acc[2] += a0 * b2f_lo(v0.y) + a1 * b2f_lo(v1.y) + a2 * b2f_lo(v2.y) + a3 * b2f_lo(v3.y);
            acc[3] += a0 * b2f_hi(v0.y) + a1 * b2f_hi(v1.y) + a2 * b2f_hi(v2.y) + a3 * b2f_hi(v3.y);
            acc[4] += a0 * b2f_lo(v0.z) + a1 * b2f_lo(v1.z) + a2 * b2f_lo(v2.z) + a3 * b2f_lo(v3.z);
            acc[5] += a0 * b2f_hi(v0.z) + a1 * b2f_hi(v1.z) + a2 * b2f_hi(v2.z) + a3 * b2f_hi(v3.z);
            acc[6] += a0 * b2f_lo(v0.w) + a1 * b2f_lo(v1.w) + a2 * b2f_lo(v2.w) + a3 * b2f_lo(v3.w);
            acc[7] += a0 * b2f_hi(v0.w) + a1 * b2f_hi(v1.w) + a2 * b2f_hi(v2.w) + a3 * b2f_hi(v3.w);
        }
        for (; i < end; i += 2) {
            int s = srcs[i];
            uint4 v = *(const uint4*)&h1b[(size_t)s * C1 + cb];
            float a = alds[wid][i - start][hc];
            acc[0] += a * b2f_lo(v.x); acc[1] += a * b2f_hi(v.x);
            acc[2] += a * b2f_lo(v.y); acc[3] += a * b2f_hi(v.y);
            acc[4] += a * b2f_lo(v.z); acc[5] += a * b2f_hi(v.z);
            acc[6] += a * b2f_lo(v.w); acc[7] += a * b2f_hi(v.w);
        }
    } else {
        // rare slow path: recompute alpha inline
        float mxB = __shfl(mx, hc << 4);
        float invB = __shfl(inv, hc << 4);
        float sdstB = __shfl(sdstA, hc << 4);
        for (; i < end; i += 2) {
            int s = srcs[i];
            uint4 v = *(const uint4*)&h1b[(size_t)s * C1 + cb];
            float e = ssrc1[s * HEADS + hc] + sdstB;
            e = e > 0.f ? e : NEG_SLOPE * e;
            float a = __expf(e - mxB) * invB;
            acc[0] += a * b2f_lo(v.x); acc[1] += a * b2f_hi(v.x);
            acc[2] += a * b2f_lo(v.y); acc[3] += a * b2f_hi(v.y);
            acc[4] += a * b2f_lo(v.z); acc[5] += a * b2f_hi(v.z);
            acc[6] += a * b2f_lo(v.w); acc[7] += a * b2f_hi(v.w);
        }
    }
#pragma unroll
    for (int j = 0; j < 8; ++j) acc[j] += __shfl_xor(acc[j], 32);
    if (half == 0) {
        float4 ba = *(const float4*)&b1[cb];
        float4 bbv = *(const float4*)&b1[cb + 4];
        float v[8];
        v[0] = acc[0] + ba.x;  v[1] = acc[1] + ba.y;
        v[2] = acc[2] + ba.z;  v[3] = acc[3] + ba.w;
        v[4] = acc[4] + bbv.x; v[5] = acc[5] + bbv.y;
        v[6] = acc[6] + bbv.z; v[7] = acc[7] + bbv.w;
        bf16x8 o;
#pragma unroll
        for (int j = 0; j < 8; ++j) {
            float t = v[j] > 0.f ? v[j] : (__expf(v[j]) - 1.f);
            o[j] = (short)f2b(t);
        }
        *(bf16x8*)&out1b[(size_t)d * C1 + cb] = o;
    }
}

// ------- GEMM2 (MFMA): h2[N,16] = out1b[N,256] @ W2b  + fused scores -------
__global__ __launch_bounds__(256) void gemm2_mfma(const unsigned short* __restrict__ out1b,
                                                  const unsigned short* __restrict__ w2b,
                                                  const float* __restrict__ a_src2,
                                                  const float* __restrict__ a_dst2,
                                                  float* __restrict__ h2,
                                                  float* __restrict__ ssrc2,
                                                  float* __restrict__ sdst2, int M) {
    __shared__ char ab[64 * 528];
    int tid = threadIdx.x;
    int m0 = blockIdx.x * 64;
#pragma unroll
    for (int r = 0; r < 8; ++r) {
        int byte = r * 4096 + tid * 16;
        int row = byte >> 9, col = byte & 511;
        uint4 v = make_uint4(0u, 0u, 0u, 0u);
        if (m0 + row < M)
            v = *(const uint4*)((const char*)out1b + (size_t)(m0 + row) * 512 + col);
        *(uint4*)(ab + row * 528 + col) = v;
    }
    int wv = tid >> 6, l = tid & 63;
    int lm = l & 15, lk = l >> 4;
    bf16x8 bfr[8];
#pragma unroll
    for (int kk = 0; kk < 8; ++kk)
        bfr[kk] = *(const bf16x8*)&w2b[lm * 256 + lk * 8 + kk * 32];
    __syncthreads();
    f32x4 acc = (f32x4){0.f, 0.f, 0.f, 0.f};
    const char* base = ab + (wv * 16 + lm) * 528 + lk * 16;
#pragma unroll
    for (int kk = 0; kk < 8; ++kk) {
        bf16x8 af = *(const bf16x8*)(base + kk * 64);
        acc = __builtin_amdgcn_mfma_f32_16x16x32_bf16(af, bfr[kk], acc, 0, 0, 0);
    }
    float asc = a_src2[lm], adc = a_dst2[lm];
#pragma unroll
    for (int r = 0; r < 4; ++r) {
        int grow = m0 + wv * 16 + lk * 4 + r;
        float v = acc[r];
        float ps = v * asc, pd = v * adc;
#pragma unroll
        for (int o = 1; o < 16; o <<= 1) {
            ps += __shfl_xor(ps, o);
            pd += __shfl_xor(pd, o);
        }
        if (grow < M) {
            h2[(size_t)grow * OUT_CH + lm] = v;
            if (lm == 0) {
                ssrc2[grow] = ps;
                sdst2[grow] = pd;
            }
        }
    }
}

// ------- fused layer-2: softmax (A, alpha->LDS) + gather + bias (B) --------
__global__ __launch_bounds__(256) void agg2_fused(const float* __restrict__ h2,
                                                  const float* __restrict__ ssrc2,
                                                  const float* __restrict__ sdst2,
                                                  const int* __restrict__ row_start,
                                                  const int* __restrict__ srcs,
                                                  const float* __restrict__ b2,
                                                  float* __restrict__ out) {
    __shared__ float alds[4][128];   // 2KB
    int wid = threadIdx.x >> 6;
    int d = blockIdx.x * 4 + wid;
    int l = threadIdx.x & 63;
    int start = row_start[d], end = row_start[d + 1];
    int deg = end - start;
    float sdst = sdst2[d];
    auto comp = [&](int i) -> float {
        int s = srcs[i];
        float e = ssrc2[s] + sdst;
        return e > 0.f ? e : NEG_SLOPE * e;
    };
    float e0 = NEGINF, e1 = NEGINF;
    int i0 = start + l;
    if (i0 < end) e0 = comp(i0);
    if (i0 + 64 < end) e1 = comp(i0 + 64);
    float mx = fmaxf(e0, e1);
    for (int i = i0 + 128; i < end; i += 64) mx = fmaxf(mx, comp(i));
#pragma unroll
    for (int o = 1; o < 64; o <<= 1) mx = fmaxf(mx, __shfl_xor(mx, o));
    float s0 = __expf(e0 - mx), s1 = __expf(e1 - mx);
    float ssum = s0 + s1;
    for (int i = i0 + 128; i < end; i += 64) ssum += __expf(comp(i) - mx);
#pragma unroll
    for (int o = 1; o < 64; o <<= 1) ssum += __shfl_xor(ssum, o);
    float inv = 1.f / (ssum + EPS_SM);
    alds[wid][l] = s0 * inv;
    alds[wid][l + 64] = s1 * inv;

    // phase B: 16 edge-slots x 4 lanes, float4 gathers
    int slot = l >> 2;
    int c4 = (l & 3) * 4;
    float4 acc = make_float4(0.f, 0.f, 0.f, 0.f);
    if (deg <= 128) {
        for (int i = start + slot; i < end; i += 16) {
            int s = srcs[i];
            float a = alds[wid][i - start];
            float4 v = *(const float4*)&h2[(size_t)s * OUT_CH + c4];
            acc.x += a * v.x; acc.y += a * v.y; acc.z += a * v.z; acc.w += a * v.w;
        }
    } else {
        for (int i = start + slot; i < end; i += 16) {
            int s = srcs[i];
            float e = ssrc2[s] + sdst;
            e = e > 0.f ? e : NEG_SLOPE * e;
            float a = __expf(e - mx) * inv;
            float4 v = *(const float4*)&h2[(size_t)s * OUT_CH + c4];
            acc.x += a * v.x; acc.y += a * v.y; acc.z += a * v.z; acc.w += a * v.w;
        }
    }
#pragma unroll
    for (int o = 4; o < 64; o <<= 1) {
        acc.x += __shfl_xor(acc.x, o);
        acc.y += __shfl_xor(acc.y, o);
        acc.z += __shfl_xor(acc.z, o);
        acc.w += __shfl_xor(acc.w, o);
    }
    if (l < 4) {
        float4 bb = *(const float4*)&b2[c4];
        float4 r = make_float4(acc.x + bb.x, acc.y + bb.y, acc.z + bb.z, acc.w + bb.w);
        *(float4*)&out[(size_t)d * OUT_CH + c4] = r;
    }
}

extern "C" void kernel_launch(void* const* d_in, const int* in_sizes, int n_in,
                              void* d_out, int out_size, void* d_ws, size_t ws_size,
                              hipStream_t stream) {
    const float* x      = (const float*)d_in[0];
    const int*   ei     = (const int*)d_in[1];
    const float* W1     = (const float*)d_in[2];
    const float* a_src1 = (const float*)d_in[3];
    const float* a_dst1 = (const float*)d_in[4];
    const float* b1     = (const float*)d_in[5];
    const float* W2     = (const float*)d_in[6];
    const float* a_src2 = (const float*)d_in[7];
    const float* a_dst2 = (const float*)d_in[8];
    const float* b2     = (const float*)d_in[9];
    float* out = (float*)d_out;

    const int E = in_sizes[1] / 2;
    const int Etot = E + NN;
    const int* src_arr = ei;
    const int* dst_arr = ei + E;

    size_t off = 0;
    auto carve = [&](size_t bytes) -> void* {
        void* r = (char*)d_ws + off;
        off += (bytes + 255) & ~(size_t)255;
        return r;
    };
    unsigned short* h1b  = (unsigned short*)carve((size_t)NN * C1 * 2);
    unsigned short* out1b= (unsigned short*)carve((size_t)NN * C1 * 2);
    unsigned short* w1t  = (unsigned short*)carve((size_t)IN_CH * C1 * 2);
    unsigned short* w2b  = (unsigned short*)carve((size_t)C1 * OUT_CH * 2);
    unsigned short* waSDt= (unsigned short*)carve((size_t)16 * 128 * 2);
    float* ssrc1 = (float*)carve((size_t)NN * HEADS * 4);
    float* sdst1 = (float*)carve((size_t)NN * HEADS * 4);
    float* h2    = (float*)carve((size_t)NN * OUT_CH * 4);
    float* ssrc2 = (float*)carve((size_t)NN * 4);
    float* sdst2 = (float*)carve((size_t)NN * 4);
    int* rowst   = (int*)carve((size_t)(NN + 1) * 4);
    int* srcs    = (int*)carve((size_t)Etot * 4);
    unsigned int* ebuf = (unsigned int*)carve((size_t)Etot * 4);
    int* bcount  = (int*)carve((size_t)NBUK * 4);
    int* bbase   = (int*)carve((size_t)(NBUK + 1) * 4);
    int* bcursor = (int*)carve((size_t)NBUK * 4);

    // ---- CSR build via buckets ----
    hipMemsetAsync(bcount, 0, (size_t)NBUK * 4, stream);
    bucket_count<<<256, 256, 0, stream>>>(dst_arr, bcount, Etot, E);
    bucket_scan<<<1, 256, 0, stream>>>(bcount, bbase, bcursor, rowst, Etot);
    bucket_scatter<<<256, 256, 0, stream>>>(src_arr, dst_arr, bcursor, ebuf, Etot, E);
    bucket_csr<<<NBUK, 256, 0, stream>>>(ebuf, bbase, rowst, srcs);

    // ---- weights prep ----
    cvt_weights<<<145, 256, 0, stream>>>(W1, W2, a_src1, a_dst1, w1t, w2b, waSDt);

    // ---- layer 1 ----
    gemm1_mfma<<<(NN + 63) / 64, 256, 0, stream>>>(x, w1t, waSDt, h1b, ssrc1, sdst1, NN);
    agg1_fused<<<NN / 4, 256, 0, stream>>>(h1b, ssrc1, sdst1, rowst, srcs, b1, out1b);

    // ---- layer 2 ----
    gemm2_mfma<<<(NN + 63) / 64, 256, 0, stream>>>(out1b, w2b, a_src2, a_dst2,
                                                   h2, ssrc2, sdst2, NN);
    agg2_fused<<<NN / 4, 256, 0, stream>>>(h2, ssrc2, sdst2, rowst, srcs, b2, out);
}